// Round 3
// baseline (3890.750 us; speedup 1.0000x reference)
//
#include <hip/hip_runtime.h>
#include <hip/hip_bf16.h>
#include <hip/hip_fp16.h>

// Performer (FAVOR+) attention forward — MFMA version.
// B=2, N=4096, H=16, D=64, M=266 features, DIM=1024.
// I/O fp32; internal Q/K/V/attn bf16, kdash fp16.

#define B_   2
#define N_   4096
#define H_   16
#define D_   64
#define M_   266
#define MP_  272     // M padded to 17*16
#define DIM_ 1024
#define RT_  8192    // B_*N_
#define BH_  32      // B_*H_
#define DDS  273     // LDS stride for dd rows

typedef __attribute__((ext_vector_type(8))) short s8v;   // 8 x bf16
typedef __attribute__((ext_vector_type(4))) float f4v;   // 4 x fp32 (MFMA acc)

__device__ __forceinline__ float  b2f(__hip_bfloat16 x){ return __bfloat162float(x); }
__device__ __forceinline__ __hip_bfloat16 f2b(float x){ return __float2bfloat16(x); }
__device__ __forceinline__ ushort f2bu(float x){ __hip_bfloat16 h = __float2bfloat16(x); return *(ushort*)&h; }

constexpr float NORMC  = 0.35355339059327379f;  // 64^-0.25
constexpr float RATIOC = 0.06131393f;           // 266^-0.5
constexpr float DIAGC  = 0.0625f;               // 0.5 * 64^-0.5
constexpr float EPSC   = 1e-4f;

// order-preserving float<->uint encode for atomicMax over signed floats
__device__ __forceinline__ unsigned encf(float x){
    unsigned b = __float_as_uint(x);
    return (b & 0x80000000u) ? ~b : (b | 0x80000000u);
}
__device__ __forceinline__ float decf(unsigned u){
    unsigned b = (u & 0x80000000u) ? (u ^ 0x80000000u) : ~u;
    return __uint_as_float(b);
}

__device__ __forceinline__ void stf(float* p, float v){ *p = v; }
__device__ __forceinline__ void stf(__hip_bfloat16* p, float v){ *p = f2b(v); }

// ---------------------------------------------------------------------------
// Cast kernels (fp32 -> bf16)
// ---------------------------------------------------------------------------
__global__ void cast_x(const float* __restrict__ s, ushort* __restrict__ d){
    const int i = (blockIdx.x * 256 + threadIdx.x) * 8;   // n = RT_*DIM_ exact
    const float4 a = *(const float4*)&s[i];
    const float4 b = *(const float4*)&s[i + 4];
    ushort4 lo, hi;
    lo.x = f2bu(a.x); lo.y = f2bu(a.y); lo.z = f2bu(a.z); lo.w = f2bu(a.w);
    hi.x = f2bu(b.x); hi.y = f2bu(b.y); hi.z = f2bu(b.z); hi.w = f2bu(b.w);
    *(ushort4*)&d[i]     = lo;
    *(ushort4*)&d[i + 4] = hi;
}

__global__ void cast_w(const float* s0, const float* s1, const float* s2, const float* s3,
                       ushort* d0, ushort* d1, ushort* d2, ushort* d3){
    const float* s; ushort* d;
    switch (blockIdx.y) {
        case 0: s = s0; d = d0; break;
        case 1: s = s1; d = d1; break;
        case 2: s = s2; d = d2; break;
        default: s = s3; d = d3; break;
    }
    const int i = (blockIdx.x * 256 + threadIdx.x) * 8;   // n = 1<<20 exact
    const float4 a = *(const float4*)&s[i];
    const float4 b = *(const float4*)&s[i + 4];
    ushort4 lo, hi;
    lo.x = f2bu(a.x); lo.y = f2bu(a.y); lo.z = f2bu(a.z); lo.w = f2bu(a.w);
    hi.x = f2bu(b.x); hi.y = f2bu(b.y); hi.z = f2bu(b.z); hi.w = f2bu(b.w);
    *(ushort4*)&d[i]     = lo;
    *(ushort4*)&d[i + 4] = hi;
}

// projb[m][d] = bf16(NORMC * proj[m][d]), zero-padded to MP_ rows
__global__ void cast_proj(const float* __restrict__ p, ushort* __restrict__ pb){
    const int i = blockIdx.x * 256 + threadIdx.x;
    if (i >= MP_ * 64) return;
    const int m = i >> 6, dc = i & 63;
    const float v = (m < M_) ? NORMC * p[m * 64 + dc] : 0.f;
    pb[i] = f2bu(v);
}

// ---------------------------------------------------------------------------
// 128x128 MFMA GEMM: C[r,c] = sum_k A[r,k]*Bw[c,k] (+bias[c]), K=1024.
// A,Bw bf16 row-major-over-k; C bf16 or fp32. 256 thr = 4 waves, each wave a
// 64x64 quadrant = 4x4 grid of 16x16x32 MFMAs. DIAG: per-head sum-of-squares
// (wave quadrant cols == exactly one head) -> diag[row*16 + head].
// ---------------------------------------------------------------------------
template<bool DIAG, bool BIAS, typename TC>
__launch_bounds__(256)
__global__ void gemm128(const ushort* __restrict__ A, const ushort* __restrict__ Bw,
                        const float* __restrict__ bias, TC* __restrict__ C,
                        float* __restrict__ diag)
{
    __shared__ ushort As[128 * 32];
    __shared__ ushort Bs[128 * 32];

    const int tid  = threadIdx.x;
    const int lane = tid & 63, wave = tid >> 6;
    const int col  = lane & 15, quad = lane >> 4;
    const int wm   = (wave & 1) * 64, wn = (wave >> 1) * 64;
    const int r0   = blockIdx.y * 128, c0 = blockIdx.x * 128;

    const int f0 = tid * 8, f1 = f0 + 2048;       // LDS elem offsets (flat row*32+kc)
    const int row0 = f0 >> 5, kc0 = f0 & 31;      // rows 0..63 / 64..127
    const size_t aoff0 = (size_t)(r0 + row0) * DIM_ + kc0;
    const size_t aoff1 = (size_t)(r0 + 64 + row0) * DIM_ + kc0;
    const size_t boff0 = (size_t)(c0 + row0) * DIM_ + kc0;
    const size_t boff1 = (size_t)(c0 + 64 + row0) * DIM_ + kc0;

    f4v acc[4][4];
    #pragma unroll
    for (int i = 0; i < 4; ++i)
        #pragma unroll
        for (int j = 0; j < 4; ++j) acc[i][j] = (f4v){0.f, 0.f, 0.f, 0.f};

    for (int kk = 0; kk < DIM_; kk += 32) {
        *(uint4*)&As[f0] = *(const uint4*)&A[aoff0 + kk];
        *(uint4*)&As[f1] = *(const uint4*)&A[aoff1 + kk];
        *(uint4*)&Bs[f0] = *(const uint4*)&Bw[boff0 + kk];
        *(uint4*)&Bs[f1] = *(const uint4*)&Bw[boff1 + kk];
        __syncthreads();
        s8v af[4], bf[4];
        #pragma unroll
        for (int i = 0; i < 4; ++i)
            af[i] = *(const s8v*)&As[(wm + i * 16 + col) * 32 + quad * 8];
        #pragma unroll
        for (int j = 0; j < 4; ++j)
            bf[j] = *(const s8v*)&Bs[(wn + j * 16 + col) * 32 + quad * 8];
        #pragma unroll
        for (int i = 0; i < 4; ++i)
            #pragma unroll
            for (int j = 0; j < 4; ++j)
                acc[i][j] = __builtin_amdgcn_mfma_f32_16x16x32_bf16(af[i], bf[j], acc[i][j], 0, 0, 0);
        __syncthreads();
    }

    // Epilogue. C/D layout (m89-verified): col = lane&15 (n), row = quad*4+reg (m).
    float bb[4] = {0.f, 0.f, 0.f, 0.f};
    if (BIAS) {
        #pragma unroll
        for (int j = 0; j < 4; ++j) bb[j] = bias[c0 + wn + j * 16 + col];
    }
    #pragma unroll
    for (int i = 0; i < 4; ++i) {
        #pragma unroll
        for (int r = 0; r < 4; ++r) {
            const size_t grow = (size_t)(r0 + wm + i * 16 + quad * 4 + r);
            #pragma unroll
            for (int j = 0; j < 4; ++j)
                stf(&C[grow * DIM_ + c0 + wn + j * 16 + col], acc[i][j][r] + bb[j]);
        }
    }
    if (DIAG) {
        const int hglob = (c0 + wn) >> 6;   // wave quadrant == one head
        #pragma unroll
        for (int i = 0; i < 4; ++i) {
            #pragma unroll
            for (int r = 0; r < 4; ++r) {
                float s = 0.f;
                #pragma unroll
                for (int j = 0; j < 4; ++j) s += acc[i][j][r] * acc[i][j][r];
                s += __shfl_xor(s, 1); s += __shfl_xor(s, 2);
                s += __shfl_xor(s, 4); s += __shfl_xor(s, 8);
                if (col == 0)
                    diag[(size_t)(r0 + wm + i * 16 + quad * 4 + r) * H_ + hglob] = DIAGC * s;
            }
        }
    }
}

// ---------------------------------------------------------------------------
// kdash[bh][n][MP_] (fp16) = K_head @ projb^T  (K=64), fused global-max ->
// atomicMax(kmaxb[bh]). 64 n-rows per block; wave w = rows w*16..+15, all 17
// m-tiles. proj panel LDS-resident.
// ---------------------------------------------------------------------------
__launch_bounds__(256)
__global__ void dashk_kernel(const ushort* __restrict__ X, const ushort* __restrict__ projb,
                             __half* __restrict__ dash, unsigned* __restrict__ kmaxb)
{
    __shared__ ushort Bl[MP_ * 64];   // 34816 B
    __shared__ float wmx[4];
    const int tid  = threadIdx.x;
    const int lane = tid & 63, wave = tid >> 6;
    const int col  = lane & 15, quad = lane >> 4;
    const int bh   = blockIdx.y, b = bh >> 4, h = bh & 15;
    const int n0   = blockIdx.x * 64;

    for (int i = tid * 8; i < MP_ * 64; i += 2048)
        *(uint4*)&Bl[i] = *(const uint4*)&projb[i];
    __syncthreads();

    const size_t arow = ((size_t)(b * N_ + n0 + wave * 16 + col)) * DIM_ + h * 64 + quad * 8;
    const s8v af0 = *(const s8v*)&X[arow];
    const s8v af1 = *(const s8v*)&X[arow + 32];

    f4v acc[17];
    #pragma unroll
    for (int t = 0; t < 17; ++t) {
        const s8v bf0 = *(const s8v*)&Bl[(t * 16 + col) * 64 + quad * 8];
        const s8v bf1 = *(const s8v*)&Bl[(t * 16 + col) * 64 + 32 + quad * 8];
        f4v a = (f4v){0.f, 0.f, 0.f, 0.f};
        a = __builtin_amdgcn_mfma_f32_16x16x32_bf16(af0, bf0, a, 0, 0, 0);
        a = __builtin_amdgcn_mfma_f32_16x16x32_bf16(af1, bf1, a, 0, 0, 0);
        acc[t] = a;
    }

    float mx = -3.4e38f;
    #pragma unroll
    for (int t = 0; t < 17; ++t) {
        const int m = t * 16 + col;
        #pragma unroll
        for (int r = 0; r < 4; ++r) {
            const int gn = n0 + wave * 16 + quad * 4 + r;
            dash[((size_t)bh * N_ + gn) * MP_ + m] = __float2half(acc[t][r]);
            if (m < M_) mx = fmaxf(mx, acc[t][r]);
        }
    }
    #pragma unroll
    for (int o = 32; o > 0; o >>= 1) mx = fmaxf(mx, __shfl_xor(mx, o));
    if (lane == 0) wmx[wave] = mx;
    __syncthreads();
    if (tid == 0)
        atomicMax(&kmaxb[bh], encf(fmaxf(fmaxf(wmx[0], wmx[1]), fmaxf(wmx[2], wmx[3]))));
}

// ---------------------------------------------------------------------------
// ctx[bh][m][e] += sum_n kp[n,m]*v[n,e]; kcs[bh][m] += sum_n kp[n,m].
// kp from materialized kdash (fp16). Thread t owns m=t. Grid (16, 32).
// ---------------------------------------------------------------------------
__launch_bounds__(320)
__global__ void kctx2(const __half* __restrict__ kdash, const __hip_bfloat16* __restrict__ Vb,
                      const float* __restrict__ diagK, const unsigned* __restrict__ kmaxb,
                      float* __restrict__ ctx, float* __restrict__ kcs)
{
    __shared__ float kdl[4][MP_];
    __shared__ float vrow[4][64];
    __shared__ float dg[4];
    const int tid = threadIdx.x;
    const int bh  = blockIdx.y, b = bh >> 4, h = bh & 15;
    const int n0  = blockIdx.x * 256;
    const float kmax = decf(kmaxb[bh]);

    float acc[64] = {};
    float accs = 0.f;

    for (int n = 0; n < 256; n += 4) {
        const int gn0 = n0 + n;
        __syncthreads();
        for (int idx = tid; idx < 4 * MP_; idx += 320) {
            const int g = idx / MP_, m = idx - g * MP_;
            if (m < M_)
                kdl[g][m] = __half2float(kdash[((size_t)bh * N_ + gn0 + g) * MP_ + m]);
        }
        if (tid < 256) {
            vrow[tid >> 6][tid & 63] =
                b2f(Vb[((size_t)(b * N_ + gn0 + (tid >> 6))) * DIM_ + h * 64 + (tid & 63)]);
        } else if (tid < 260) {
            dg[tid - 256] = diagK[((size_t)(b * N_ + gn0 + tid - 256)) * H_ + h];
        }
        __syncthreads();
        if (tid < M_) {
            float kp[4];
            #pragma unroll
            for (int g = 0; g < 4; ++g) {
                kp[g] = RATIOC * (__expf(kdl[g][tid] - dg[g] - kmax) + EPSC);
                accs += kp[g];
            }
            #pragma unroll
            for (int i = 0; i < 16; ++i) {
                const float4 v0 = ((const float4*)vrow[0])[i];
                const float4 v1 = ((const float4*)vrow[1])[i];
                const float4 v2 = ((const float4*)vrow[2])[i];
                const float4 v3 = ((const float4*)vrow[3])[i];
                acc[4*i+0] += kp[0]*v0.x + kp[1]*v1.x + kp[2]*v2.x + kp[3]*v3.x;
                acc[4*i+1] += kp[0]*v0.y + kp[1]*v1.y + kp[2]*v2.y + kp[3]*v3.y;
                acc[4*i+2] += kp[0]*v0.z + kp[1]*v1.z + kp[2]*v2.z + kp[3]*v3.z;
                acc[4*i+3] += kp[0]*v0.w + kp[1]*v1.w + kp[2]*v2.w + kp[3]*v3.w;
            }
        }
    }
    if (tid < M_) {
        float* cp = ctx + ((size_t)bh * M_ + tid) * 64;
        #pragma unroll
        for (int e = 0; e < 64; ++e) atomicAdd(&cp[e], acc[e]);
        atomicAdd(&kcs[(size_t)bh * M_ + tid], accs);
    }
}

// ---------------------------------------------------------------------------
// Fused Q path, one 32-row tile per block (grid 128 x 32):
// in-kernel MFMA dash -> LDS fp32 -> rowmax -> qp=exp -> den -> qp@ctx -> Ab.
// ---------------------------------------------------------------------------
__launch_bounds__(256)
__global__ void qout2(const ushort* __restrict__ Qb, const ushort* __restrict__ projb,
                      const float* __restrict__ diagQ, const float* __restrict__ ctx,
                      const float* __restrict__ kcs, __hip_bfloat16* __restrict__ Ab)
{
    __shared__ float ddl[32 * DDS];   // 34944 B
    __shared__ float cst[32 * 64];    // 8192 B
    __shared__ float kcl[M_];
    __shared__ float rml[32], dil[32], dgl[32];

    const int tid  = threadIdx.x;
    const int lane = tid & 63, wave = tid >> 6;
    const int col  = lane & 15, quad = lane >> 4;
    const int bh   = blockIdx.y, b = bh >> 4, h = bh & 15;
    const int n0   = blockIdx.x * 32;

    for (int i = tid; i < M_; i += 256) kcl[i] = kcs[(size_t)bh * M_ + i];
    if (tid < 32) dgl[tid] = diagQ[((size_t)(b * N_ + n0 + tid)) * H_ + h];

    // fused dash: ntile = wave&1 (rows), m-tile halves split by wave>>1
    const int ntile = wave & 1;
    const int ts = (wave >> 1) ? 9 : 0;
    const int te = (wave >> 1) ? 17 : 9;
    const size_t arow = ((size_t)(b * N_ + n0 + ntile * 16 + col)) * DIM_ + h * 64 + quad * 8;
    const s8v af0 = *(const s8v*)&Qb[arow];
    const s8v af1 = *(const s8v*)&Qb[arow + 32];

    f4v acc[9];
    #pragma unroll
    for (int u = 0; u < 9; ++u) {
        const int t = ts + u;
        if (t < te) {
            const s8v bf0 = *(const s8v*)&projb[(t * 16 + col) * 64 + quad * 8];
            const s8v bf1 = *(const s8v*)&projb[(t * 16 + col) * 64 + 32 + quad * 8];
            f4v a = (f4v){0.f, 0.f, 0.f, 0.f};
            a = __builtin_amdgcn_mfma_f32_16x16x32_bf16(af0, bf0, a, 0, 0, 0);
            a = __builtin_amdgcn_mfma_f32_16x16x32_bf16(af1, bf1, a, 0, 0, 0);
            acc[u] = a;
        }
    }
    #pragma unroll
    for (int u = 0; u < 9; ++u) {
        const int t = ts + u;
        const int m = t * 16 + col;
        if (t < te && m < M_) {
            const int rr = ntile * 16 + quad * 4;
            #pragma unroll
            for (int r = 0; r < 4; ++r) ddl[(rr + r) * DDS + m] = acc[u][r];
        }
    }
    __syncthreads();

    // rowmax (8 lanes/row)
    {
        const int r = tid >> 3, p = tid & 7;
        float mv = -3.4e38f;
        for (int mm = p; mm < M_; mm += 8) mv = fmaxf(mv, ddl[r * DDS + mm]);
        #pragma unroll
        for (int o = 4; o > 0; o >>= 1) mv = fmaxf(mv, __shfl_down(mv, o, 8));
        if (p == 0) rml[r] = mv;
    }
    __syncthreads();

    // qp = ratio*(exp(dd - diag - rowmax) + eps), in place
    for (int idx = tid; idx < 32 * M_; idx += 256) {
        const int r = idx / M_;
        const int mm = idx - r * M_;
        ddl[r * DDS + mm] = RATIOC * (__expf(ddl[r * DDS + mm] - dgl[r] - rml[r]) + EPSC);
    }
    __syncthreads();

    // den = qp . kcs -> 1/den
    {
        const int r = tid >> 3, p = tid & 7;
        float s = 0.f;
        for (int mm = p; mm < M_; mm += 8) s += ddl[r * DDS + mm] * kcl[mm];
        #pragma unroll
        for (int o = 4; o > 0; o >>= 1) s += __shfl_down(s, o, 8);
        if (p == 0) dil[r] = 1.0f / fmaxf(s, 1e-30f);
    }
    __syncthreads();

    // out tile = qp @ ctx (2 rows x 4 cols per thread)
    float acc2[2][4] = {};
    const int r0l = (tid >> 4) * 2, e0 = (tid & 15) * 4;
    for (int mb = 0; mb < M_; mb += 32) {
        const int cnt = (M_ - mb < 32) ? (M_ - mb) : 32;
        for (int idx = tid; idx < cnt * 64; idx += 256)
            cst[idx] = ctx[((size_t)bh * M_ + mb + (idx >> 6)) * 64 + (idx & 63)];
        __syncthreads();
        for (int mm = 0; mm < cnt; ++mm) {
            const float a0 = ddl[(r0l + 0) * DDS + mb + mm];
            const float a1 = ddl[(r0l + 1) * DDS + mb + mm];
            const float4 bv = *(const float4*)&cst[mm * 64 + e0];
            acc2[0][0] += a0 * bv.x; acc2[0][1] += a0 * bv.y;
            acc2[0][2] += a0 * bv.z; acc2[0][3] += a0 * bv.w;
            acc2[1][0] += a1 * bv.x; acc2[1][1] += a1 * bv.y;
            acc2[1][2] += a1 * bv.z; acc2[1][3] += a1 * bv.w;
        }
        __syncthreads();
    }
    #pragma unroll
    for (int i = 0; i < 2; ++i) {
        const float di = dil[r0l + i];
        const size_t row = (size_t)(b * N_ + n0 + r0l + i);
        #pragma unroll
        for (int j = 0; j < 4; ++j)
            Ab[row * DIM_ + h * 64 + e0 + j] = f2b(acc2[i][j] * di);
    }
}

// ---------------------------------------------------------------------------
extern "C" void kernel_launch(void* const* d_in, const int* in_sizes, int n_in,
                              void* d_out, int out_size, void* d_ws, size_t ws_size,
                              hipStream_t stream)
{
    const float* x    = (const float*)d_in[0];
    const float* Wq   = (const float*)d_in[1];
    const float* Wk   = (const float*)d_in[2];
    const float* Wv   = (const float*)d_in[3];
    const float* Wo   = (const float*)d_in[4];
    const float* bo   = (const float*)d_in[5];
    const float* proj = (const float*)d_in[6];

    char* ws = (char*)d_ws;
    size_t o = 0;
    ushort* xb    = (ushort*)(ws + o); o += (size_t)RT_ * DIM_ * 2;
    ushort* Wqb   = (ushort*)(ws + o); o += (size_t)DIM_ * DIM_ * 2;
    ushort* Wkb   = (ushort*)(ws + o); o += (size_t)DIM_ * DIM_ * 2;
    ushort* Wvb   = (ushort*)(ws + o); o += (size_t)DIM_ * DIM_ * 2;
    ushort* Wob   = (ushort*)(ws + o); o += (size_t)DIM_ * DIM_ * 2;
    ushort* projb = (ushort*)(ws + o); o += (size_t)MP_ * 64 * 2;
    ushort* Qb    = (ushort*)(ws + o); o += (size_t)RT_ * DIM_ * 2;
    ushort* Kb    = (ushort*)(ws + o); o += (size_t)RT_ * DIM_ * 2;
    ushort* Vb    = (ushort*)(ws + o); o += (size_t)RT_ * DIM_ * 2;
    ushort* Ab    = (ushort*)(ws + o); o += (size_t)RT_ * DIM_ * 2;
    __half* kdash = (__half*)(ws + o); o += (size_t)BH_ * N_ * MP_ * 2;
    float*    ctx   = (float*)(ws + o);    o += (size_t)BH_ * M_ * 64 * 4;
    float*    kcs   = (float*)(ws + o);    o += (size_t)BH_ * M_ * 4;
    unsigned* kmaxb = (unsigned*)(ws + o); o += 128;
    float*    diagQ = (float*)(ws + o);    o += (size_t)RT_ * H_ * 4;
    float*    diagK = (float*)(ws + o);    o += (size_t)RT_ * H_ * 4;

    // zero ctx + kcs + kmaxb (contiguous). kmaxb==0 decodes below any real max.
    const size_t zbytes = (size_t)BH_ * M_ * 64 * 4 + (size_t)BH_ * M_ * 4 + 128;
    hipMemsetAsync(ctx, 0, zbytes, stream);

    cast_x<<<dim3(RT_ * DIM_ / 2048), 256, 0, stream>>>(x, xb);
    cast_w<<<dim3(DIM_ * DIM_ / 2048, 4), 256, 0, stream>>>(Wq, Wk, Wv, Wo, Wqb, Wkb, Wvb, Wob);
    cast_proj<<<dim3((MP_ * 64 + 255) / 256), 256, 0, stream>>>(proj, projb);

    const dim3 ggrid(DIM_ / 128, RT_ / 128);   // (8, 64)
    gemm128<true,  false, __hip_bfloat16><<<ggrid, 256, 0, stream>>>(xb, Wqb, nullptr, (__hip_bfloat16*)Qb, diagQ);
    gemm128<true,  false, __hip_bfloat16><<<ggrid, 256, 0, stream>>>(xb, Wkb, nullptr, (__hip_bfloat16*)Kb, diagK);
    gemm128<false, false, __hip_bfloat16><<<ggrid, 256, 0, stream>>>(xb, Wvb, nullptr, (__hip_bfloat16*)Vb, nullptr);

    dashk_kernel<<<dim3(N_ / 64, BH_), 256, 0, stream>>>(Kb, projb, kdash, kmaxb);
    kctx2<<<dim3(16, BH_), 320, 0, stream>>>(kdash, (const __hip_bfloat16*)Vb, diagK, kmaxb, ctx, kcs);
    qout2<<<dim3(N_ / 32, BH_), 256, 0, stream>>>(Qb, projb, diagQ, ctx, kcs, (__hip_bfloat16*)Ab);

    gemm128<false, true, float><<<ggrid, 256, 0, stream>>>(Ab, Wob, bo, (float*)d_out, nullptr);
}

// Round 4
// 402.234 us; speedup vs baseline: 9.6728x; 9.6728x over previous
//
#include <hip/hip_runtime.h>
#include <hip/hip_bf16.h>
#include <hip/hip_fp16.h>

// Performer (FAVOR+) attention forward — all-MFMA pipeline.
// B=2, N=4096, H=16, D=64, M=266 (padded 288), DIM=1024.
// I/O fp32; internals bf16 (kdash fp16).

#define B_   2
#define N_   4096
#define H_   16
#define M_   266
#define MP_  288     // M padded to 9*32 (clean 32-k-steps)
#define DIM_ 1024
#define RT_  8192    // B_*N_
#define BH_  32      // B_*H_
#define LSA  40      // LDS stride (elems) for kctx A/B tiles
#define LSB  296     // LDS stride (elems) for qout ctxT rows

typedef __attribute__((ext_vector_type(8))) short s8v;   // 8 x bf16
typedef __attribute__((ext_vector_type(4))) float f4v;   // MFMA acc

__device__ __forceinline__ float  b2f(__hip_bfloat16 x){ return __bfloat162float(x); }
__device__ __forceinline__ ushort f2bu(float x){ __hip_bfloat16 h = __float2bfloat16(x); return *(ushort*)&h; }
__device__ __forceinline__ float  bu2f(ushort u){ return __uint_as_float((unsigned)u << 16); }

constexpr float NORMC  = 0.35355339059327379f;  // 64^-0.25
constexpr float RATIOC = 0.06131393f;           // 266^-0.5
constexpr float DIAGC  = 0.0625f;               // 0.5 * 64^-0.5
constexpr float EPSC   = 1e-4f;

__device__ __forceinline__ unsigned encf(float x){
    unsigned b = __float_as_uint(x);
    return (b & 0x80000000u) ? ~b : (b | 0x80000000u);
}
__device__ __forceinline__ float decf(unsigned u){
    unsigned b = (u & 0x80000000u) ? (u ^ 0x80000000u) : ~u;
    return __uint_as_float(b);
}

__device__ __forceinline__ void stf(float* p, float v){ *p = v; }
__device__ __forceinline__ void stf(__hip_bfloat16* p, float v){ *p = __float2bfloat16(v); }

// ---------------------------------------------------------------------------
// Casts
// ---------------------------------------------------------------------------
__global__ void cast_x(const float* __restrict__ s, ushort* __restrict__ d){
    const int i = (blockIdx.x * 256 + threadIdx.x) * 8;
    const float4 a = *(const float4*)&s[i];
    const float4 b = *(const float4*)&s[i + 4];
    ushort4 lo, hi;
    lo.x = f2bu(a.x); lo.y = f2bu(a.y); lo.z = f2bu(a.z); lo.w = f2bu(a.w);
    hi.x = f2bu(b.x); hi.y = f2bu(b.y); hi.z = f2bu(b.z); hi.w = f2bu(b.w);
    *(ushort4*)&d[i]     = lo;
    *(ushort4*)&d[i + 4] = hi;
}

__global__ void cast_w(const float* s0, const float* s1, const float* s2, const float* s3,
                       ushort* d0, ushort* d1, ushort* d2, ushort* d3){
    const float* s; ushort* d;
    switch (blockIdx.y) {
        case 0: s = s0; d = d0; break;
        case 1: s = s1; d = d1; break;
        case 2: s = s2; d = d2; break;
        default: s = s3; d = d3; break;
    }
    const int i = (blockIdx.x * 256 + threadIdx.x) * 8;
    const float4 a = *(const float4*)&s[i];
    const float4 b = *(const float4*)&s[i + 4];
    ushort4 lo, hi;
    lo.x = f2bu(a.x); lo.y = f2bu(a.y); lo.z = f2bu(a.z); lo.w = f2bu(a.w);
    hi.x = f2bu(b.x); hi.y = f2bu(b.y); hi.z = f2bu(b.z); hi.w = f2bu(b.w);
    *(ushort4*)&d[i]     = lo;
    *(ushort4*)&d[i + 4] = hi;
}

// projb[m][d] = bf16(NORMC*proj[m][d]), zero rows m in [266,288)
__global__ void cast_proj(const float* __restrict__ p, ushort* __restrict__ pb){
    const int i = blockIdx.x * 256 + threadIdx.x;
    if (i >= MP_ * 64) return;
    const int m = i >> 6, dc = i & 63;
    pb[i] = f2bu((m < M_) ? NORMC * p[m * 64 + dc] : 0.f);
}

// ---------------------------------------------------------------------------
// 128x128 MFMA GEMM (verified R3): C[r,c] = sum_k A[r,k]*Bw[c,k] (+bias).
// ---------------------------------------------------------------------------
template<bool DIAG, bool BIAS, typename TC>
__launch_bounds__(256)
__global__ void gemm128(const ushort* __restrict__ A, const ushort* __restrict__ Bw,
                        const float* __restrict__ bias, TC* __restrict__ C,
                        float* __restrict__ diag)
{
    __shared__ ushort As[128 * 32];
    __shared__ ushort Bs[128 * 32];

    const int tid  = threadIdx.x;
    const int lane = tid & 63, wave = tid >> 6;
    const int col  = lane & 15, quad = lane >> 4;
    const int wm   = (wave & 1) * 64, wn = (wave >> 1) * 64;
    const int r0   = blockIdx.y * 128, c0 = blockIdx.x * 128;

    const int f0 = tid * 8, f1 = f0 + 2048;
    const int row0 = f0 >> 5, kc0 = f0 & 31;
    const size_t aoff0 = (size_t)(r0 + row0) * DIM_ + kc0;
    const size_t aoff1 = (size_t)(r0 + 64 + row0) * DIM_ + kc0;
    const size_t boff0 = (size_t)(c0 + row0) * DIM_ + kc0;
    const size_t boff1 = (size_t)(c0 + 64 + row0) * DIM_ + kc0;

    f4v acc[4][4];
    #pragma unroll
    for (int i = 0; i < 4; ++i)
        #pragma unroll
        for (int j = 0; j < 4; ++j) acc[i][j] = (f4v){0.f, 0.f, 0.f, 0.f};

    for (int kk = 0; kk < DIM_; kk += 32) {
        *(uint4*)&As[f0] = *(const uint4*)&A[aoff0 + kk];
        *(uint4*)&As[f1] = *(const uint4*)&A[aoff1 + kk];
        *(uint4*)&Bs[f0] = *(const uint4*)&Bw[boff0 + kk];
        *(uint4*)&Bs[f1] = *(const uint4*)&Bw[boff1 + kk];
        __syncthreads();
        s8v af[4], bf[4];
        #pragma unroll
        for (int i = 0; i < 4; ++i)
            af[i] = *(const s8v*)&As[(wm + i * 16 + col) * 32 + quad * 8];
        #pragma unroll
        for (int j = 0; j < 4; ++j)
            bf[j] = *(const s8v*)&Bs[(wn + j * 16 + col) * 32 + quad * 8];
        #pragma unroll
        for (int i = 0; i < 4; ++i)
            #pragma unroll
            for (int j = 0; j < 4; ++j)
                acc[i][j] = __builtin_amdgcn_mfma_f32_16x16x32_bf16(af[i], bf[j], acc[i][j], 0, 0, 0);
        __syncthreads();
    }

    float bb[4] = {0.f, 0.f, 0.f, 0.f};
    if (BIAS) {
        #pragma unroll
        for (int j = 0; j < 4; ++j) bb[j] = bias[c0 + wn + j * 16 + col];
    }
    #pragma unroll
    for (int i = 0; i < 4; ++i) {
        #pragma unroll
        for (int r = 0; r < 4; ++r) {
            const size_t grow = (size_t)(r0 + wm + i * 16 + quad * 4 + r);
            #pragma unroll
            for (int j = 0; j < 4; ++j)
                stf(&C[grow * DIM_ + c0 + wn + j * 16 + col], acc[i][j][r] + bb[j]);
        }
    }
    if (DIAG) {
        const int hglob = (c0 + wn) >> 6;
        #pragma unroll
        for (int i = 0; i < 4; ++i) {
            #pragma unroll
            for (int r = 0; r < 4; ++r) {
                float s = 0.f;
                #pragma unroll
                for (int j = 0; j < 4; ++j) s += acc[i][j][r] * acc[i][j][r];
                s += __shfl_xor(s, 1); s += __shfl_xor(s, 2);
                s += __shfl_xor(s, 4); s += __shfl_xor(s, 8);
                if (col == 0)
                    diag[(size_t)(r0 + wm + i * 16 + quad * 4 + r) * H_ + hglob] = DIAGC * s;
            }
        }
    }
}

// ---------------------------------------------------------------------------
// kdash[bh][n][MP_] (fp16, cols<272) = K_head @ projb^T, fused global-max.
// ---------------------------------------------------------------------------
__launch_bounds__(256)
__global__ void dashk_kernel(const ushort* __restrict__ X, const ushort* __restrict__ projb,
                             __half* __restrict__ dash, unsigned* __restrict__ kmaxb)
{
    __shared__ ushort Bl[MP_ * 64];   // 36864 B
    __shared__ float wmx[4];
    const int tid  = threadIdx.x;
    const int lane = tid & 63, wave = tid >> 6;
    const int col  = lane & 15, quad = lane >> 4;
    const int bh   = blockIdx.y, b = bh >> 4, h = bh & 15;
    const int n0   = blockIdx.x * 64;

    for (int i = tid * 8; i < MP_ * 64; i += 2048)
        *(uint4*)&Bl[i] = *(const uint4*)&projb[i];
    __syncthreads();

    const size_t arow = ((size_t)(b * N_ + n0 + wave * 16 + col)) * DIM_ + h * 64 + quad * 8;
    const s8v af0 = *(const s8v*)&X[arow];
    const s8v af1 = *(const s8v*)&X[arow + 32];

    float mx = -3.4e38f;
    #pragma unroll
    for (int t = 0; t < 17; ++t) {
        const s8v bf0 = *(const s8v*)&Bl[(t * 16 + col) * 64 + quad * 8];
        const s8v bf1 = *(const s8v*)&Bl[(t * 16 + col) * 64 + 32 + quad * 8];
        f4v a = (f4v){0.f, 0.f, 0.f, 0.f};
        a = __builtin_amdgcn_mfma_f32_16x16x32_bf16(af0, bf0, a, 0, 0, 0);
        a = __builtin_amdgcn_mfma_f32_16x16x32_bf16(af1, bf1, a, 0, 0, 0);
        const int m = t * 16 + col;
        #pragma unroll
        for (int r = 0; r < 4; ++r) {
            const int gn = n0 + wave * 16 + quad * 4 + r;
            dash[((size_t)bh * N_ + gn) * MP_ + m] = __float2half(a[r]);
            if (m < M_) mx = fmaxf(mx, a[r]);
        }
    }
    #pragma unroll
    for (int o = 32; o > 0; o >>= 1) mx = fmaxf(mx, __shfl_xor(mx, o));
    if (lane == 0) wmx[wave] = mx;
    __syncthreads();
    if (tid == 0)
        atomicMax(&kmaxb[bh], encf(fmaxf(fmaxf(wmx[0], wmx[1]), fmaxf(wmx[2], wmx[3]))));
}

// ---------------------------------------------------------------------------
// ctx[bh][m][e] += kp^T @ V  via MFMA; kcs[m] += row sums. Grid (16, 32).
// Stages kp (exp applied, transposed) and V^T into LDS each 32-n step.
// ---------------------------------------------------------------------------
__launch_bounds__(256)
__global__ void kctx_mfma(const __half* __restrict__ kdash, const ushort* __restrict__ Vb,
                          const float* __restrict__ diagK, const unsigned* __restrict__ kmaxb,
                          float* __restrict__ ctx, float* __restrict__ kcs)
{
    __shared__ ushort Al[MP_ * LSA];  // 23040 B
    __shared__ ushort Bl[64 * LSA];   // 5120 B

    const int tid  = threadIdx.x;
    const int lane = tid & 63, wave = tid >> 6;
    const int col  = lane & 15, quad = lane >> 4;
    const int bh   = blockIdx.y, b = bh >> 4, h = bh & 15;
    const int n0   = blockIdx.x * 256;
    const int nn   = tid >> 3, sub = tid & 7;
    const float kmax = decf(kmaxb[bh]);

    f4v acc[18];
    #pragma unroll
    for (int t = 0; t < 18; ++t) acc[t] = (f4v){0.f, 0.f, 0.f, 0.f};
    float kcs0 = 0.f, kcs1 = 0.f;

    for (int ks = 0; ks < 8; ++ks) {
        const int gn = n0 + ks * 32 + nn;
        const float dgv = diagK[((size_t)(b * N_ + gn)) * H_ + h];
        const __half* kr = &kdash[((size_t)bh * N_ + gn) * MP_];
        #pragma unroll
        for (int mi = 0; mi < MP_ / 8; ++mi) {
            const int m = sub + mi * 8;
            float v = 0.f;
            if (m < M_)
                v = RATIOC * (__expf(__half2float(kr[m]) - dgv - kmax) + EPSC);
            Al[m * LSA + nn] = f2bu(v);
        }
        {
            const s8v vv = *(const s8v*)&Vb[((size_t)(b * N_ + gn)) * DIM_ + h * 64 + sub * 8];
            #pragma unroll
            for (int j = 0; j < 8; ++j)
                Bl[(sub * 8 + j) * LSA + nn] = ((const ushort*)&vv)[j];
        }
        __syncthreads();
        // kcs row sums (rows tid and 256+tid)
        {
            const s8v* rp = (const s8v*)&Al[tid * LSA];
            float s = 0.f;
            #pragma unroll
            for (int j = 0; j < 4; ++j) {
                const s8v v8 = rp[j];
                #pragma unroll
                for (int e = 0; e < 8; ++e) s += bu2f(((const ushort*)&v8)[e]);
            }
            kcs0 += s;
            if (tid < 32) {
                const s8v* rp2 = (const s8v*)&Al[(256 + tid) * LSA];
                float s2 = 0.f;
                #pragma unroll
                for (int j = 0; j < 4; ++j) {
                    const s8v v8 = rp2[j];
                    #pragma unroll
                    for (int e = 0; e < 8; ++e) s2 += bu2f(((const ushort*)&v8)[e]);
                }
                kcs1 += s2;
            }
        }
        const s8v bfr = *(const s8v*)&Bl[(wave * 16 + col) * LSA + quad * 8];
        #pragma unroll
        for (int t = 0; t < 18; ++t) {
            const s8v afr = *(const s8v*)&Al[(t * 16 + col) * LSA + quad * 8];
            acc[t] = __builtin_amdgcn_mfma_f32_16x16x32_bf16(afr, bfr, acc[t], 0, 0, 0);
        }
        __syncthreads();
    }
    #pragma unroll
    for (int t = 0; t < 18; ++t) {
        #pragma unroll
        for (int r = 0; r < 4; ++r) {
            const int m = t * 16 + quad * 4 + r;
            atomicAdd(&ctx[((size_t)bh * MP_ + m) * 64 + wave * 16 + col], acc[t][r]);
        }
    }
    atomicAdd(&kcs[(size_t)bh * MP_ + tid], kcs0);
    if (tid < 32) atomicAdd(&kcs[(size_t)bh * MP_ + 256 + tid], kcs1);
}

// ---------------------------------------------------------------------------
// ctxT[bh][e][m] (bf16) = ctx[bh][m][e]
// ---------------------------------------------------------------------------
__global__ void ctx_finalize(const float* __restrict__ ctx, ushort* __restrict__ ctxT)
{
    const int bh = blockIdx.x, tid = threadIdx.x;
    for (int flat = tid; flat < MP_ * 64; flat += 256) {
        const int m = flat >> 6, e = flat & 63;
        ctxT[((size_t)bh * 64 + e) * MP_ + m] = f2bu(ctx[(size_t)bh * MP_ * 64 + flat]);
    }
}

// ---------------------------------------------------------------------------
// qp[bh][n][MP_] (bf16) = ratio*(exp(Q@proj^T - diag - rowmax)+eps), pads 0;
// deninv[bh][n] = 1/(qp . kcs). Fully fused, MFMA dash, in-wave rowmax.
// ---------------------------------------------------------------------------
__launch_bounds__(256)
__global__ void qdash_kernel(const ushort* __restrict__ Qb, const ushort* __restrict__ projb,
                             const float* __restrict__ diagQ, const float* __restrict__ kcs,
                             ushort* __restrict__ qp, float* __restrict__ deninv)
{
    __shared__ ushort Bl[MP_ * 64];   // 36864 B
    __shared__ float kcl[MP_];
    const int tid  = threadIdx.x;
    const int lane = tid & 63, wave = tid >> 6;
    const int col  = lane & 15, quad = lane >> 4;
    const int bh   = blockIdx.y, b = bh >> 4, h = bh & 15;
    const int n0   = blockIdx.x * 64;

    for (int i = tid * 8; i < MP_ * 64; i += 2048)
        *(uint4*)&Bl[i] = *(const uint4*)&projb[i];
    for (int i = tid; i < MP_; i += 256) kcl[i] = kcs[(size_t)bh * MP_ + i];
    __syncthreads();

    const size_t arow = ((size_t)(b * N_ + n0 + wave * 16 + col)) * DIM_ + h * 64 + quad * 8;
    const s8v af0 = *(const s8v*)&Qb[arow];
    const s8v af1 = *(const s8v*)&Qb[arow + 32];

    f4v acc[17];
    #pragma unroll
    for (int t = 0; t < 17; ++t) {
        const s8v bf0 = *(const s8v*)&Bl[(t * 16 + col) * 64 + quad * 8];
        const s8v bf1 = *(const s8v*)&Bl[(t * 16 + col) * 64 + 32 + quad * 8];
        f4v a = (f4v){0.f, 0.f, 0.f, 0.f};
        a = __builtin_amdgcn_mfma_f32_16x16x32_bf16(af0, bf0, a, 0, 0, 0);
        a = __builtin_amdgcn_mfma_f32_16x16x32_bf16(af1, bf1, a, 0, 0, 0);
        acc[t] = a;
    }

    // rowmax + diag per r (valid m only: t<16, or t==16 && col<10)
    float dgr[4], rmx[4];
    #pragma unroll
    for (int r = 0; r < 4; ++r) {
        const int gn = n0 + wave * 16 + quad * 4 + r;
        dgr[r] = diagQ[((size_t)(b * N_ + gn)) * H_ + h];
        float mx = -3.4e38f;
        #pragma unroll
        for (int t = 0; t < 16; ++t) mx = fmaxf(mx, acc[t][r]);
        if (col < 10) mx = fmaxf(mx, acc[16][r]);
        mx = fmaxf(mx, __shfl_xor(mx, 1));
        mx = fmaxf(mx, __shfl_xor(mx, 2));
        mx = fmaxf(mx, __shfl_xor(mx, 4));
        mx = fmaxf(mx, __shfl_xor(mx, 8));
        rmx[r] = mx;
    }

    float den[4] = {0.f, 0.f, 0.f, 0.f};
    #pragma unroll
    for (int t = 0; t < 17; ++t) {
        const int m = t * 16 + col;
        const float kc = kcl[m];
        #pragma unroll
        for (int r = 0; r < 4; ++r) {
            float v = 0.f;
            if (m < M_)
                v = RATIOC * (__expf(acc[t][r] - dgr[r] - rmx[r]) + EPSC);
            acc[t][r] = v;
            den[r] += v * kc;
        }
    }

    // write qp (+ zero pads 272..287)
    #pragma unroll
    for (int r = 0; r < 4; ++r) {
        const size_t rowb = ((size_t)bh * N_ + n0 + wave * 16 + quad * 4 + r) * MP_;
        #pragma unroll
        for (int t = 0; t < 17; ++t)
            qp[rowb + t * 16 + col] = f2bu(acc[t][r]);
        if (col < 8) *(uint*)&qp[rowb + 272 + col * 2] = 0u;
    }

    #pragma unroll
    for (int r = 0; r < 4; ++r) {
        float d = den[r];
        d += __shfl_xor(d, 1); d += __shfl_xor(d, 2);
        d += __shfl_xor(d, 4); d += __shfl_xor(d, 8);
        if (col == 0)
            deninv[(size_t)bh * N_ + n0 + wave * 16 + quad * 4 + r] = 1.0f / fmaxf(d, 1e-30f);
    }
}

// ---------------------------------------------------------------------------
// Ab[n][h*64+e] = deninv[n] * (qp[n][:] @ ctxT[e][:])  via MFMA. Grid (64,32).
// ---------------------------------------------------------------------------
__launch_bounds__(256)
__global__ void qout_mfma(const ushort* __restrict__ qp, const ushort* __restrict__ ctxT,
                          const float* __restrict__ deninv, ushort* __restrict__ Ab)
{
    __shared__ ushort Cl[64 * LSB];   // 37888 B
    __shared__ float dinv[64];
    const int tid  = threadIdx.x;
    const int lane = tid & 63, wave = tid >> 6;
    const int col  = lane & 15, quad = lane >> 4;
    const int bh   = blockIdx.y, b = bh >> 4, h = bh & 15;
    const int n0   = blockIdx.x * 64;

    for (int i = tid * 8; i < 64 * MP_; i += 2048) {
        const int e = i / MP_, m = i - e * MP_;
        *(uint4*)&Cl[e * LSB + m] = *(const uint4*)&ctxT[(size_t)bh * 64 * MP_ + i];
    }
    if (tid < 64) dinv[tid] = deninv[(size_t)bh * N_ + n0 + tid];
    __syncthreads();

    f4v acc[4];
    #pragma unroll
    for (int j = 0; j < 4; ++j) acc[j] = (f4v){0.f, 0.f, 0.f, 0.f};

    const ushort* qrow = &qp[((size_t)bh * N_ + n0 + wave * 16 + col) * MP_];
    #pragma unroll
    for (int kk = 0; kk < 9; ++kk) {
        const s8v afr = *(const s8v*)&qrow[kk * 32 + quad * 8];
        #pragma unroll
        for (int j = 0; j < 4; ++j) {
            const s8v bfr = *(const s8v*)&Cl[(j * 16 + col) * LSB + kk * 32 + quad * 8];
            acc[j] = __builtin_amdgcn_mfma_f32_16x16x32_bf16(afr, bfr, acc[j], 0, 0, 0);
        }
    }
    #pragma unroll
    for (int j = 0; j < 4; ++j) {
        #pragma unroll
        for (int r = 0; r < 4; ++r) {
            const int n = wave * 16 + quad * 4 + r;
            Ab[((size_t)(b * N_ + n0 + n)) * DIM_ + h * 64 + j * 16 + col] =
                f2bu(acc[j][r] * dinv[n]);
        }
    }
}

// ---------------------------------------------------------------------------
extern "C" void kernel_launch(void* const* d_in, const int* in_sizes, int n_in,
                              void* d_out, int out_size, void* d_ws, size_t ws_size,
                              hipStream_t stream)
{
    const float* x    = (const float*)d_in[0];
    const float* Wq   = (const float*)d_in[1];
    const float* Wk   = (const float*)d_in[2];
    const float* Wv   = (const float*)d_in[3];
    const float* Wo   = (const float*)d_in[4];
    const float* bo   = (const float*)d_in[5];
    const float* proj = (const float*)d_in[6];

    char* ws = (char*)d_ws;
    size_t o = 0;
    ushort* xb    = (ushort*)(ws + o); o += (size_t)RT_ * DIM_ * 2;
    ushort* Wqb   = (ushort*)(ws + o); o += (size_t)DIM_ * DIM_ * 2;
    ushort* Wkb   = (ushort*)(ws + o); o += (size_t)DIM_ * DIM_ * 2;
    ushort* Wvb   = (ushort*)(ws + o); o += (size_t)DIM_ * DIM_ * 2;
    ushort* Wob   = (ushort*)(ws + o); o += (size_t)DIM_ * DIM_ * 2;
    ushort* projb = (ushort*)(ws + o); o += (size_t)MP_ * 64 * 2;
    ushort* Qb    = (ushort*)(ws + o); o += (size_t)RT_ * DIM_ * 2;
    ushort* Kb    = (ushort*)(ws + o); o += (size_t)RT_ * DIM_ * 2;
    ushort* Vb    = (ushort*)(ws + o); o += (size_t)RT_ * DIM_ * 2;
    ushort* Ab    = (ushort*)(ws + o); o += (size_t)RT_ * DIM_ * 2;
    __half* kdash = (__half*)(ws + o); o += (size_t)BH_ * N_ * MP_ * 2;  // aliased by qp
    ushort* qpb   = (ushort*)kdash;     // qp reuses kdash (dead after kctx_mfma)
    float*    ctx   = (float*)(ws + o);    o += (size_t)BH_ * MP_ * 64 * 4;
    float*    kcs   = (float*)(ws + o);    o += (size_t)BH_ * MP_ * 4;
    unsigned* kmaxb = (unsigned*)(ws + o); o += 128;
    float*    diagQ = (float*)(ws + o);    o += (size_t)RT_ * H_ * 4;
    float*    diagK = (float*)(ws + o);    o += (size_t)RT_ * H_ * 4;
    ushort*   ctxT  = (ushort*)(ws + o);   o += (size_t)BH_ * 64 * MP_ * 2;
    float*    dninv = (float*)(ws + o);    o += (size_t)BH_ * N_ * 4;

    // zero ctx + kcs + kmaxb (contiguous)
    const size_t zbytes = (size_t)BH_ * MP_ * 64 * 4 + (size_t)BH_ * MP_ * 4 + 128;
    hipMemsetAsync(ctx, 0, zbytes, stream);

    cast_x<<<dim3(RT_ * DIM_ / 2048), 256, 0, stream>>>(x, xb);
    cast_w<<<dim3(DIM_ * DIM_ / 2048, 4), 256, 0, stream>>>(Wq, Wk, Wv, Wo, Wqb, Wkb, Wvb, Wob);
    cast_proj<<<dim3(MP_ * 64 / 256), 256, 0, stream>>>(proj, projb);

    const dim3 ggrid(DIM_ / 128, RT_ / 128);   // (8, 64)
    gemm128<true,  false, __hip_bfloat16><<<ggrid, 256, 0, stream>>>(xb, Wqb, nullptr, (__hip_bfloat16*)Qb, diagQ);
    gemm128<true,  false, __hip_bfloat16><<<ggrid, 256, 0, stream>>>(xb, Wkb, nullptr, (__hip_bfloat16*)Kb, diagK);
    gemm128<false, false, __hip_bfloat16><<<ggrid, 256, 0, stream>>>(xb, Wvb, nullptr, (__hip_bfloat16*)Vb, nullptr);

    dashk_kernel<<<dim3(N_ / 64, BH_), 256, 0, stream>>>(Kb, projb, kdash, kmaxb);
    kctx_mfma<<<dim3(16, BH_), 256, 0, stream>>>(kdash, Vb, diagK, kmaxb, ctx, kcs);
    ctx_finalize<<<dim3(BH_), 256, 0, stream>>>(ctx, ctxT);
    qdash_kernel<<<dim3(N_ / 64, BH_), 256, 0, stream>>>(Qb, projb, diagQ, kcs, qpb, dninv);
    qout_mfma<<<dim3(N_ / 64, BH_), 256, 0, stream>>>(qpb, ctxT, dninv, Ab);

    gemm128<false, true, float><<<ggrid, 256, 0, stream>>>(Ab, Wob, bo, (float*)d_out, nullptr);
}

// Round 6
// 369.086 us; speedup vs baseline: 10.5416x; 1.0898x over previous
//
#include <hip/hip_runtime.h>
#include <hip/hip_bf16.h>
#include <hip/hip_fp16.h>

// Performer (FAVOR+) attention forward — all-MFMA pipeline, v2.1.
// B=2, N=4096, H=16, D=64, M=266 (padded 288), DIM=1024.
// I/O fp32; internals bf16. R6: fix R5's uninitialized Kp tile 17 (odd waves
// now cover t=9..17 so every Kp row is written; pads get kp=0).

#define B_   2
#define N_   4096
#define H_   16
#define M_   266
#define MP_  288     // M padded to 18*16
#define DIM_ 1024
#define RT_  8192    // B_*N_
#define BH_  32      // B_*H_
#define LKN  40      // kctx LDS stride (n-dim 32 padded)
#define LSB  296     // qout ctxT row stride

typedef __attribute__((ext_vector_type(8))) short s8v;   // 8 x bf16
typedef __attribute__((ext_vector_type(4))) float f4v;   // MFMA acc

__device__ __forceinline__ ushort f2bu(float x){ __hip_bfloat16 h = __float2bfloat16(x); return *(ushort*)&h; }

constexpr float NORMC  = 0.35355339059327379f;  // 64^-0.25
constexpr float RATIOC = 0.06131393f;           // 266^-0.5
constexpr float DIAGC  = 0.0625f;               // 0.5 * 64^-0.5
constexpr float EPSC   = 1e-4f;

__device__ __forceinline__ unsigned encf(float x){
    unsigned b = __float_as_uint(x);
    return (b & 0x80000000u) ? ~b : (b | 0x80000000u);
}
__device__ __forceinline__ float decf(unsigned u){
    unsigned b = (u & 0x80000000u) ? (u ^ 0x80000000u) : ~u;
    return __uint_as_float(b);
}

__device__ __forceinline__ void stf(float* p, float v){ *p = v; }
__device__ __forceinline__ void stf(__hip_bfloat16* p, float v){ *p = __float2bfloat16(v); }

// async global->LDS, 16B per lane; lds dest wave-uniform base (+lane*16 by HW)
__device__ __forceinline__ void gl_lds16(const ushort* g, ushort* l){
    __builtin_amdgcn_global_load_lds(
        (const __attribute__((address_space(1))) unsigned int*)(const unsigned int*)g,
        (__attribute__((address_space(3))) unsigned int*)(unsigned int*)l,
        16, 0, 0);
}

// ---------------------------------------------------------------------------
// Casts
// ---------------------------------------------------------------------------
__global__ void cast_x(const float* __restrict__ s, ushort* __restrict__ d){
    const int i = (blockIdx.x * 256 + threadIdx.x) * 8;
    const float4 a = *(const float4*)&s[i];
    const float4 b = *(const float4*)&s[i + 4];
    ushort4 lo, hi;
    lo.x = f2bu(a.x); lo.y = f2bu(a.y); lo.z = f2bu(a.z); lo.w = f2bu(a.w);
    hi.x = f2bu(b.x); hi.y = f2bu(b.y); hi.z = f2bu(b.z); hi.w = f2bu(b.w);
    *(ushort4*)&d[i]     = lo;
    *(ushort4*)&d[i + 4] = hi;
}

__global__ void cast_w(const float* s0, const float* s1, const float* s2, const float* s3,
                       ushort* d0, ushort* d1, ushort* d2, ushort* d3){
    const float* s; ushort* d;
    switch (blockIdx.y) {
        case 0: s = s0; d = d0; break;
        case 1: s = s1; d = d1; break;
        case 2: s = s2; d = d2; break;
        default: s = s3; d = d3; break;
    }
    const int i = (blockIdx.x * 256 + threadIdx.x) * 8;
    const float4 a = *(const float4*)&s[i];
    const float4 b = *(const float4*)&s[i + 4];
    ushort4 lo, hi;
    lo.x = f2bu(a.x); lo.y = f2bu(a.y); lo.z = f2bu(a.z); lo.w = f2bu(a.w);
    hi.x = f2bu(b.x); hi.y = f2bu(b.y); hi.z = f2bu(b.z); hi.w = f2bu(b.w);
    *(ushort4*)&d[i]     = lo;
    *(ushort4*)&d[i + 4] = hi;
}

__global__ void cast_proj(const float* __restrict__ p, ushort* __restrict__ pb){
    const int i = blockIdx.x * 256 + threadIdx.x;
    if (i >= MP_ * 64) return;
    const int m = i >> 6, dc = i & 63;
    pb[i] = f2bu((m < M_) ? NORMC * p[m * 64 + dc] : 0.f);
}

// ---------------------------------------------------------------------------
// 128x128 MFMA GEMM with global_load_lds staging (m97 structure).
// ---------------------------------------------------------------------------
template<bool DIAG, bool BIAS, typename TC>
__launch_bounds__(256)
__global__ void gemm128(const ushort* __restrict__ A, const ushort* __restrict__ Bw,
                        const float* __restrict__ bias, TC* __restrict__ C,
                        float* __restrict__ diag)
{
    __shared__ ushort As[128 * 32];
    __shared__ ushort Bs[128 * 32];

    const int tid  = threadIdx.x;
    const int lane = tid & 63, wave = tid >> 6;
    const int col  = lane & 15, quad = lane >> 4;
    const int wm   = (wave & 1) * 64, wn = (wave >> 1) * 64;
    const int r0   = blockIdx.y * 128, c0 = blockIdx.x * 128;

    const int f0 = tid * 8;                       // flat elem offset (16B/lane)
    const int row0 = f0 >> 5, kc0 = f0 & 31;
    const size_t aoff0 = (size_t)(r0 + row0) * DIM_ + kc0;
    const size_t aoff1 = (size_t)(r0 + 64 + row0) * DIM_ + kc0;
    const size_t boff0 = (size_t)(c0 + row0) * DIM_ + kc0;
    const size_t boff1 = (size_t)(c0 + 64 + row0) * DIM_ + kc0;
    ushort* asb0 = &As[wave * 512];        // wave-uniform LDS bases
    ushort* asb1 = &As[2048 + wave * 512];
    ushort* bsb0 = &Bs[wave * 512];
    ushort* bsb1 = &Bs[2048 + wave * 512];

    f4v acc[4][4];
    #pragma unroll
    for (int i = 0; i < 4; ++i)
        #pragma unroll
        for (int j = 0; j < 4; ++j) acc[i][j] = (f4v){0.f, 0.f, 0.f, 0.f};

    for (int kk = 0; kk < DIM_; kk += 32) {
        gl_lds16(&A[aoff0 + kk],  asb0);
        gl_lds16(&A[aoff1 + kk],  asb1);
        gl_lds16(&Bw[boff0 + kk], bsb0);
        gl_lds16(&Bw[boff1 + kk], bsb1);
        __syncthreads();
        s8v af[4], bf[4];
        #pragma unroll
        for (int i = 0; i < 4; ++i)
            af[i] = *(const s8v*)&As[(wm + i * 16 + col) * 32 + quad * 8];
        #pragma unroll
        for (int j = 0; j < 4; ++j)
            bf[j] = *(const s8v*)&Bs[(wn + j * 16 + col) * 32 + quad * 8];
        #pragma unroll
        for (int i = 0; i < 4; ++i)
            #pragma unroll
            for (int j = 0; j < 4; ++j)
                acc[i][j] = __builtin_amdgcn_mfma_f32_16x16x32_bf16(af[i], bf[j], acc[i][j], 0, 0, 0);
        __syncthreads();
    }

    float bb[4] = {0.f, 0.f, 0.f, 0.f};
    if (BIAS) {
        #pragma unroll
        for (int j = 0; j < 4; ++j) bb[j] = bias[c0 + wn + j * 16 + col];
    }
    #pragma unroll
    for (int i = 0; i < 4; ++i) {
        #pragma unroll
        for (int r = 0; r < 4; ++r) {
            const size_t grow = (size_t)(r0 + wm + i * 16 + quad * 4 + r);
            #pragma unroll
            for (int j = 0; j < 4; ++j)
                stf(&C[grow * DIM_ + c0 + wn + j * 16 + col], acc[i][j][r] + bb[j]);
        }
    }
    if (DIAG) {
        const int hglob = (c0 + wn) >> 6;
        #pragma unroll
        for (int i = 0; i < 4; ++i) {
            #pragma unroll
            for (int r = 0; r < 4; ++r) {
                float s = 0.f;
                #pragma unroll
                for (int j = 0; j < 4; ++j) s += acc[i][j][r] * acc[i][j][r];
                s += __shfl_xor(s, 1); s += __shfl_xor(s, 2);
                s += __shfl_xor(s, 4); s += __shfl_xor(s, 8);
                if (col == 0)
                    diag[(size_t)(r0 + wm + i * 16 + quad * 4 + r) * H_ + hglob] = DIAGC * s;
            }
        }
    }
}

// ---------------------------------------------------------------------------
// Pass 1: global max over (n,m) of kdash per bh. No stores. Grid (16, 32).
// ---------------------------------------------------------------------------
__launch_bounds__(256)
__global__ void kmax_mfma(const ushort* __restrict__ Kb, const ushort* __restrict__ projb,
                          unsigned* __restrict__ kmaxb)
{
    __shared__ ushort Pl[MP_ * 64];   // 36864 B
    __shared__ float wmx[4];
    const int tid  = threadIdx.x;
    const int lane = tid & 63, wave = tid >> 6;
    const int col  = lane & 15, quad = lane >> 4;
    const int bh   = blockIdx.y, b = bh >> 4, h = bh & 15;

    for (int i = tid * 8; i < MP_ * 64; i += 2048)
        *(uint4*)&Pl[i] = *(const uint4*)&projb[i];
    __syncthreads();

    float mx = -3.4e38f;
    for (int ni = 0; ni < 4; ++ni) {
        const int nb = blockIdx.x * 256 + ni * 64;
        const size_t arow = ((size_t)(b * N_ + nb + wave * 16 + col)) * DIM_ + h * 64 + quad * 8;
        const s8v af0 = *(const s8v*)&Kb[arow];
        const s8v af1 = *(const s8v*)&Kb[arow + 32];
        #pragma unroll
        for (int t = 0; t < 17; ++t) {
            const s8v bf0 = *(const s8v*)&Pl[(t * 16 + col) * 64 + quad * 8];
            const s8v bf1 = *(const s8v*)&Pl[(t * 16 + col) * 64 + 32 + quad * 8];
            f4v a = (f4v){0.f, 0.f, 0.f, 0.f};
            a = __builtin_amdgcn_mfma_f32_16x16x32_bf16(af0, bf0, a, 0, 0, 0);
            a = __builtin_amdgcn_mfma_f32_16x16x32_bf16(af1, bf1, a, 0, 0, 0);
            if (t * 16 + col < M_) {
                #pragma unroll
                for (int r = 0; r < 4; ++r) mx = fmaxf(mx, a[r]);
            }
        }
    }
    #pragma unroll
    for (int o = 32; o > 0; o >>= 1) mx = fmaxf(mx, __shfl_xor(mx, o));
    if (lane == 0) wmx[wave] = mx;
    __syncthreads();
    if (tid == 0)
        atomicMax(&kmaxb[bh], encf(fmaxf(fmaxf(wmx[0], wmx[1]), fmaxf(wmx[2], wmx[3]))));
}

// ---------------------------------------------------------------------------
// Pass 2: ctx[m][e] += kp^T @ V, kcs[m] += row sums. dd recomputed via MFMA,
// exp in regs, kp staged to LDS via packed writes. Grid (16, 32).
// Wave split: rowblk = wave>>1 (16 n-rows each), m-tiles 0..8 / 9..17 by
// wave parity — ALL 18 tiles written (t=17 -> kp=0, fixes R5 NaN).
// ---------------------------------------------------------------------------
__launch_bounds__(256)
__global__ void kctx_mfma(const ushort* __restrict__ Kb, const ushort* __restrict__ Vb,
                          const ushort* __restrict__ projb,
                          const float* __restrict__ diagK, const unsigned* __restrict__ kmaxb,
                          float* __restrict__ ctx, float* __restrict__ kcs)
{
    __shared__ ushort Pl[MP_ * 64];    // 36864 B (proj, resident)
    __shared__ ushort Kp[MP_ * LKN];   // 23040 B (kp^T tile [m][n32])
    __shared__ ushort Vt[64 * LKN];    //  5120 B (V^T tile [e][n32])

    const int tid  = threadIdx.x;
    const int lane = tid & 63, wave = tid >> 6;
    const int col  = lane & 15, quad = lane >> 4;
    const int bh   = blockIdx.y, b = bh >> 4, h = bh & 15;
    const int n0   = blockIdx.x * 256;
    const float kmax = decf(kmaxb[bh]);
    const int rowblk = wave >> 1;            // waves 0,1 -> n-rows 0-15; 2,3 -> 16-31
    const int t0 = (wave & 1) * 9;           // m-tiles: 0..8 / 9..17 (covers all 18)
    const int t1 = t0 + 9;

    for (int i = tid * 8; i < MP_ * 64; i += 2048)
        *(uint4*)&Pl[i] = *(const uint4*)&projb[i];

    f4v facc[18];
    #pragma unroll
    for (int t = 0; t < 18; ++t) facc[t] = (f4v){0.f, 0.f, 0.f, 0.f};
    float kcsa[9] = {};

    __syncthreads();

    for (int ks = 0; ks < 8; ++ks) {
        const int nb = n0 + ks * 32;
        // V^T stage: thread handles n = tid&31, e = (tid>>5)*8 .. +7
        {
            const int n = tid & 31, e0 = (tid >> 5) * 8;
            const s8v vv = *(const s8v*)&Vb[((size_t)(b * N_ + nb + n)) * DIM_ + h * 64 + e0];
            #pragma unroll
            for (int j = 0; j < 8; ++j) Vt[(e0 + j) * LKN + n] = ((const ushort*)&vv)[j];
        }
        // dd via MFMA: A-rows = K rows nb + rowblk*16 + col
        const size_t arow = ((size_t)(b * N_ + nb + rowblk * 16 + col)) * DIM_ + h * 64 + quad * 8;
        const s8v af0 = *(const s8v*)&Kb[arow];
        const s8v af1 = *(const s8v*)&Kb[arow + 32];
        float dgr[4];
        #pragma unroll
        for (int r = 0; r < 4; ++r)
            dgr[r] = diagK[((size_t)(b * N_ + nb + rowblk * 16 + quad * 4 + r)) * H_ + h];
        for (int t = t0; t < t1; ++t) {
            const s8v bf0 = *(const s8v*)&Pl[(t * 16 + col) * 64 + quad * 8];
            const s8v bf1 = *(const s8v*)&Pl[(t * 16 + col) * 64 + 32 + quad * 8];
            f4v a = (f4v){0.f, 0.f, 0.f, 0.f};
            a = __builtin_amdgcn_mfma_f32_16x16x32_bf16(af0, bf0, a, 0, 0, 0);
            a = __builtin_amdgcn_mfma_f32_16x16x32_bf16(af1, bf1, a, 0, 0, 0);
            const int m = t * 16 + col;
            float kp[4];
            #pragma unroll
            for (int r = 0; r < 4; ++r) {
                float v = 0.f;
                if (m < M_) v = RATIOC * (__expf(a[r] - dgr[r] - kmax) + EPSC);
                kp[r] = v;
            }
            kcsa[t - t0] += kp[0] + kp[1] + kp[2] + kp[3];
            ushort4 pk;
            pk.x = f2bu(kp[0]); pk.y = f2bu(kp[1]); pk.z = f2bu(kp[2]); pk.w = f2bu(kp[3]);
            *(ushort4*)&Kp[m * LKN + rowblk * 16 + quad * 4] = pk;   // 4 consecutive n
        }
        __syncthreads();
        // out: wave owns e-tile = wave*16, all 18 m-tiles, k = 32 (this chunk)
        const s8v bfe = *(const s8v*)&Vt[(wave * 16 + col) * LKN + quad * 8];
        #pragma unroll
        for (int t = 0; t < 18; ++t) {
            const s8v am = *(const s8v*)&Kp[(t * 16 + col) * LKN + quad * 8];
            facc[t] = __builtin_amdgcn_mfma_f32_16x16x32_bf16(am, bfe, facc[t], 0, 0, 0);
        }
        __syncthreads();
    }

    // ctx += facc  (D layout: m = t*16 + quad*4 + r, e = wave*16 + col)
    #pragma unroll
    for (int t = 0; t < 18; ++t) {
        #pragma unroll
        for (int r = 0; r < 4; ++r) {
            const int m = t * 16 + quad * 4 + r;
            atomicAdd(&ctx[((size_t)bh * MP_ + m) * 64 + wave * 16 + col], facc[t][r]);
        }
    }
    // kcs: reduce per-m partials over quads, one atomic per (wave, tile)
    for (int t = t0; t < t1; ++t) {
        float s = kcsa[t - t0];
        s += __shfl_xor(s, 16);
        s += __shfl_xor(s, 32);
        if (quad == 0) atomicAdd(&kcs[(size_t)bh * MP_ + t * 16 + col], s);
    }
}

// ---------------------------------------------------------------------------
// ctxT[bh][e][m] (bf16) = ctx[bh][m][e]
// ---------------------------------------------------------------------------
__global__ void ctx_finalize(const float* __restrict__ ctx, ushort* __restrict__ ctxT)
{
    const int bh = blockIdx.x, tid = threadIdx.x;
    for (int flat = tid; flat < MP_ * 64; flat += 256) {
        const int m = flat >> 6, e = flat & 63;
        ctxT[((size_t)bh * 64 + e) * MP_ + m] = f2bu(ctx[(size_t)bh * MP_ * 64 + flat]);
    }
}

// ---------------------------------------------------------------------------
// qp[bh][n][MP_] (bf16) + deninv. MFMA dash, in-wave rowmax. Grid (64, 32).
// ---------------------------------------------------------------------------
__launch_bounds__(256)
__global__ void qdash_kernel(const ushort* __restrict__ Qb, const ushort* __restrict__ projb,
                             const float* __restrict__ diagQ, const float* __restrict__ kcs,
                             ushort* __restrict__ qp, float* __restrict__ deninv)
{
    __shared__ ushort Bl[MP_ * 64];   // 36864 B
    __shared__ float kcl[MP_];
    const int tid  = threadIdx.x;
    const int lane = tid & 63, wave = tid >> 6;
    const int col  = lane & 15, quad = lane >> 4;
    const int bh   = blockIdx.y, b = bh >> 4, h = bh & 15;
    const int n0   = blockIdx.x * 64;

    for (int i = tid * 8; i < MP_ * 64; i += 2048)
        *(uint4*)&Bl[i] = *(const uint4*)&projb[i];
    for (int i = tid; i < MP_; i += 256) kcl[i] = kcs[(size_t)bh * MP_ + i];
    __syncthreads();

    const size_t arow = ((size_t)(b * N_ + n0 + wave * 16 + col)) * DIM_ + h * 64 + quad * 8;
    const s8v af0 = *(const s8v*)&Qb[arow];
    const s8v af1 = *(const s8v*)&Qb[arow + 32];

    f4v acc[17];
    #pragma unroll
    for (int t = 0; t < 17; ++t) {
        const s8v bf0 = *(const s8v*)&Bl[(t * 16 + col) * 64 + quad * 8];
        const s8v bf1 = *(const s8v*)&Bl[(t * 16 + col) * 64 + 32 + quad * 8];
        f4v a = (f4v){0.f, 0.f, 0.f, 0.f};
        a = __builtin_amdgcn_mfma_f32_16x16x32_bf16(af0, bf0, a, 0, 0, 0);
        a = __builtin_amdgcn_mfma_f32_16x16x32_bf16(af1, bf1, a, 0, 0, 0);
        acc[t] = a;
    }

    float dgr[4], rmx[4];
    #pragma unroll
    for (int r = 0; r < 4; ++r) {
        const int gn = n0 + wave * 16 + quad * 4 + r;
        dgr[r] = diagQ[((size_t)(b * N_ + gn)) * H_ + h];
        float mx = -3.4e38f;
        #pragma unroll
        for (int t = 0; t < 16; ++t) mx = fmaxf(mx, acc[t][r]);
        if (col < 10) mx = fmaxf(mx, acc[16][r]);
        mx = fmaxf(mx, __shfl_xor(mx, 1));
        mx = fmaxf(mx, __shfl_xor(mx, 2));
        mx = fmaxf(mx, __shfl_xor(mx, 4));
        mx = fmaxf(mx, __shfl_xor(mx, 8));
        rmx[r] = mx;
    }

    float den[4] = {0.f, 0.f, 0.f, 0.f};
    #pragma unroll
    for (int t = 0; t < 17; ++t) {
        const int m = t * 16 + col;
        const float kc = kcl[m];
        #pragma unroll
        for (int r = 0; r < 4; ++r) {
            float v = 0.f;
            if (m < M_)
                v = RATIOC * (__expf(acc[t][r] - dgr[r] - rmx[r]) + EPSC);
            acc[t][r] = v;
            den[r] += v * kc;
        }
    }

    #pragma unroll
    for (int r = 0; r < 4; ++r) {
        const size_t rowb = ((size_t)bh * N_ + n0 + wave * 16 + quad * 4 + r) * MP_;
        #pragma unroll
        for (int t = 0; t < 17; ++t)
            qp[rowb + t * 16 + col] = f2bu(acc[t][r]);
        if (col < 8) *(uint*)&qp[rowb + 272 + col * 2] = 0u;
    }

    #pragma unroll
    for (int r = 0; r < 4; ++r) {
        float d = den[r];
        d += __shfl_xor(d, 1); d += __shfl_xor(d, 2);
        d += __shfl_xor(d, 4); d += __shfl_xor(d, 8);
        if (col == 0)
            deninv[(size_t)bh * N_ + n0 + wave * 16 + quad * 4 + r] = 1.0f / fmaxf(d, 1e-30f);
    }
}

// ---------------------------------------------------------------------------
// Ab = deninv * (qp @ ctxT^T) via MFMA. Grid (64, 32).
// ---------------------------------------------------------------------------
__launch_bounds__(256)
__global__ void qout_mfma(const ushort* __restrict__ qp, const ushort* __restrict__ ctxT,
                          const float* __restrict__ deninv, ushort* __restrict__ Ab)
{
    __shared__ ushort Cl[64 * LSB];   // 37888 B
    __shared__ float dinv[64];
    const int tid  = threadIdx.x;
    const int lane = tid & 63, wave = tid >> 6;
    const int col  = lane & 15, quad = lane >> 4;
    const int bh   = blockIdx.y, b = bh >> 4, h = bh & 15;
    const int n0   = blockIdx.x * 64;

    for (int i = tid * 8; i < 64 * MP_; i += 2048) {
        const int e = i / MP_, m = i - e * MP_;
        *(uint4*)&Cl[e * LSB + m] = *(const uint4*)&ctxT[(size_t)bh * 64 * MP_ + i];
    }
    if (tid < 64) dinv[tid] = deninv[(size_t)bh * N_ + n0 + tid];
    __syncthreads();

    f4v acc[4];
    #pragma unroll
    for (int j = 0; j < 4; ++j) acc[j] = (f4v){0.f, 0.f, 0.f, 0.f};

    const ushort* qrow = &qp[((size_t)bh * N_ + n0 + wave * 16 + col) * MP_];
    #pragma unroll
    for (int kk = 0; kk < 9; ++kk) {
        const s8v afr = *(const s8v*)&qrow[kk * 32 + quad * 8];
        #pragma unroll
        for (int j = 0; j < 4; ++j) {
            const s8v bfr = *(const s8v*)&Cl[(j * 16 + col) * LSB + kk * 32 + quad * 8];
            acc[j] = __builtin_amdgcn_mfma_f32_16x16x32_bf16(afr, bfr, acc[j], 0, 0, 0);
        }
    }
    #pragma unroll
    for (int j = 0; j < 4; ++j) {
        #pragma unroll
        for (int r = 0; r < 4; ++r) {
            const int n = wave * 16 + quad * 4 + r;
            Ab[((size_t)(b * N_ + n0 + n)) * DIM_ + h * 64 + j * 16 + col] =
                f2bu(acc[j][r] * dinv[n]);
        }
    }
}

// ---------------------------------------------------------------------------
extern "C" void kernel_launch(void* const* d_in, const int* in_sizes, int n_in,
                              void* d_out, int out_size, void* d_ws, size_t ws_size,
                              hipStream_t stream)
{
    const float* x    = (const float*)d_in[0];
    const float* Wq   = (const float*)d_in[1];
    const float* Wk   = (const float*)d_in[2];
    const float* Wv   = (const float*)d_in[3];
    const float* Wo   = (const float*)d_in[4];
    const float* bo   = (const float*)d_in[5];
    const float* proj = (const float*)d_in[6];

    char* ws = (char*)d_ws;
    size_t o = 0;
    ushort* xb    = (ushort*)(ws + o); o += (size_t)RT_ * DIM_ * 2;
    ushort* Wqb   = (ushort*)(ws + o); o += (size_t)DIM_ * DIM_ * 2;
    ushort* Wkb   = (ushort*)(ws + o); o += (size_t)DIM_ * DIM_ * 2;
    ushort* Wvb   = (ushort*)(ws + o); o += (size_t)DIM_ * DIM_ * 2;
    ushort* Wob   = (ushort*)(ws + o); o += (size_t)DIM_ * DIM_ * 2;
    ushort* projb = (ushort*)(ws + o); o += (size_t)MP_ * 64 * 2;
    ushort* Qb    = (ushort*)(ws + o); o += (size_t)RT_ * DIM_ * 2;
    ushort* Kb    = (ushort*)(ws + o); o += (size_t)RT_ * DIM_ * 2;
    ushort* Vb    = (ushort*)(ws + o); o += (size_t)RT_ * DIM_ * 2;
    ushort* Ab    = (ushort*)(ws + o); o += (size_t)RT_ * DIM_ * 2;
    ushort* qpb   = (ushort*)(ws + o); o += (size_t)BH_ * N_ * MP_ * 2;
    float*    ctx   = (float*)(ws + o);    o += (size_t)BH_ * MP_ * 64 * 4;
    float*    kcs   = (float*)(ws + o);    o += (size_t)BH_ * MP_ * 4;
    unsigned* kmaxb = (unsigned*)(ws + o); o += 128;
    float*    diagQ = (float*)(ws + o);    o += (size_t)RT_ * H_ * 4;
    float*    diagK = (float*)(ws + o);    o += (size_t)RT_ * H_ * 4;
    ushort*   ctxT  = (ushort*)(ws + o);   o += (size_t)BH_ * 64 * MP_ * 2;
    float*    dninv = (float*)(ws + o);    o += (size_t)BH_ * N_ * 4;

    const size_t zbytes = (size_t)BH_ * MP_ * 64 * 4 + (size_t)BH_ * MP_ * 4 + 128;
    hipMemsetAsync(ctx, 0, zbytes, stream);

    cast_x<<<dim3(RT_ * DIM_ / 2048), 256, 0, stream>>>(x, xb);
    cast_w<<<dim3(DIM_ * DIM_ / 2048, 4), 256, 0, stream>>>(Wq, Wk, Wv, Wo, Wqb, Wkb, Wvb, Wob);
    cast_proj<<<dim3(MP_ * 64 / 256), 256, 0, stream>>>(proj, projb);

    const dim3 ggrid(DIM_ / 128, RT_ / 128);   // (8, 64)
    gemm128<true,  false, __hip_bfloat16><<<ggrid, 256, 0, stream>>>(xb, Wqb, nullptr, (__hip_bfloat16*)Qb, diagQ);
    gemm128<true,  false, __hip_bfloat16><<<ggrid, 256, 0, stream>>>(xb, Wkb, nullptr, (__hip_bfloat16*)Kb, diagK);
    gemm128<false, false, __hip_bfloat16><<<ggrid, 256, 0, stream>>>(xb, Wvb, nullptr, (__hip_bfloat16*)Vb, nullptr);

    kmax_mfma<<<dim3(16, BH_), 256, 0, stream>>>(Kb, projb, kmaxb);
    kctx_mfma<<<dim3(16, BH_), 256, 0, stream>>>(Kb, Vb, projb, diagK, kmaxb, ctx, kcs);
    ctx_finalize<<<dim3(BH_), 256, 0, stream>>>(ctx, ctxT);
    qdash_kernel<<<dim3(N_ / 64, BH_), 256, 0, stream>>>(Qb, projb, diagQ, kcs, qpb, dninv);
    qout_mfma<<<dim3(N_ / 64, BH_), 256, 0, stream>>>(qpb, ctxT, dninv, Ab);

    gemm128<false, true, float><<<ggrid, 256, 0, stream>>>(Ab, Wob, bo, (float*)d_out, nullptr);
}

// Round 7
// 324.944 us; speedup vs baseline: 11.9736x; 1.1358x over previous
//
#include <hip/hip_runtime.h>
#include <hip/hip_bf16.h>
#include <hip/hip_fp16.h>

// Performer (FAVOR+) attention forward — all-MFMA pipeline, v3.
// B=2, N=4096, H=16, D=64, M=266 (padded 288), DIM=1024.
// R7: kctx atomics -> per-chunk partial buffers + ctx_reduce;
//     qdash+qout fused (qp LDS transpose, no global round-trip).

#define B_   2
#define N_   4096
#define H_   16
#define M_   266
#define MP_  288     // M padded to 18*16
#define DIM_ 1024
#define RT_  8192    // B_*N_
#define BH_  32      // B_*H_
#define LKN  40      // kctx LDS stride (n-dim 32 padded)
#define LSB  296     // qdashout LDS row stride (288 + 8)
#define NCH  16      // kctx n-chunks per bh

typedef __attribute__((ext_vector_type(8))) short s8v;   // 8 x bf16
typedef __attribute__((ext_vector_type(4))) float f4v;   // MFMA acc

__device__ __forceinline__ ushort f2bu(float x){ __hip_bfloat16 h = __float2bfloat16(x); return *(ushort*)&h; }

constexpr float NORMC  = 0.35355339059327379f;  // 64^-0.25
constexpr float RATIOC = 0.06131393f;           // 266^-0.5
constexpr float DIAGC  = 0.0625f;               // 0.5 * 64^-0.5
constexpr float EPSC   = 1e-4f;

__device__ __forceinline__ unsigned encf(float x){
    unsigned b = __float_as_uint(x);
    return (b & 0x80000000u) ? ~b : (b | 0x80000000u);
}
__device__ __forceinline__ float decf(unsigned u){
    unsigned b = (u & 0x80000000u) ? (u ^ 0x80000000u) : ~u;
    return __uint_as_float(b);
}

__device__ __forceinline__ void stf(float* p, float v){ *p = v; }
__device__ __forceinline__ void stf(__hip_bfloat16* p, float v){ *p = __float2bfloat16(v); }

// async global->LDS, 16B per lane; lds dest wave-uniform base (+lane*16 by HW)
__device__ __forceinline__ void gl_lds16(const ushort* g, ushort* l){
    __builtin_amdgcn_global_load_lds(
        (const __attribute__((address_space(1))) unsigned int*)(const unsigned int*)g,
        (__attribute__((address_space(3))) unsigned int*)(unsigned int*)l,
        16, 0, 0);
}

// ---------------------------------------------------------------------------
// Casts
// ---------------------------------------------------------------------------
__global__ void cast_x(const float* __restrict__ s, ushort* __restrict__ d){
    const int i = (blockIdx.x * 256 + threadIdx.x) * 8;
    const float4 a = *(const float4*)&s[i];
    const float4 b = *(const float4*)&s[i + 4];
    ushort4 lo, hi;
    lo.x = f2bu(a.x); lo.y = f2bu(a.y); lo.z = f2bu(a.z); lo.w = f2bu(a.w);
    hi.x = f2bu(b.x); hi.y = f2bu(b.y); hi.z = f2bu(b.z); hi.w = f2bu(b.w);
    *(ushort4*)&d[i]     = lo;
    *(ushort4*)&d[i + 4] = hi;
}

__global__ void cast_w(const float* s0, const float* s1, const float* s2, const float* s3,
                       ushort* d0, ushort* d1, ushort* d2, ushort* d3){
    const float* s; ushort* d;
    switch (blockIdx.y) {
        case 0: s = s0; d = d0; break;
        case 1: s = s1; d = d1; break;
        case 2: s = s2; d = d2; break;
        default: s = s3; d = d3; break;
    }
    const int i = (blockIdx.x * 256 + threadIdx.x) * 8;
    const float4 a = *(const float4*)&s[i];
    const float4 b = *(const float4*)&s[i + 4];
    ushort4 lo, hi;
    lo.x = f2bu(a.x); lo.y = f2bu(a.y); lo.z = f2bu(a.z); lo.w = f2bu(a.w);
    hi.x = f2bu(b.x); hi.y = f2bu(b.y); hi.z = f2bu(b.z); hi.w = f2bu(b.w);
    *(ushort4*)&d[i]     = lo;
    *(ushort4*)&d[i + 4] = hi;
}

__global__ void cast_proj(const float* __restrict__ p, ushort* __restrict__ pb){
    const int i = blockIdx.x * 256 + threadIdx.x;
    if (i >= MP_ * 64) return;
    const int m = i >> 6, dc = i & 63;
    pb[i] = f2bu((m < M_) ? NORMC * p[m * 64 + dc] : 0.f);
}

// ---------------------------------------------------------------------------
// 128x128 MFMA GEMM with global_load_lds staging (m97 structure).
// ---------------------------------------------------------------------------
template<bool DIAG, bool BIAS, typename TC>
__launch_bounds__(256)
__global__ void gemm128(const ushort* __restrict__ A, const ushort* __restrict__ Bw,
                        const float* __restrict__ bias, TC* __restrict__ C,
                        float* __restrict__ diag)
{
    __shared__ ushort As[128 * 32];
    __shared__ ushort Bs[128 * 32];

    const int tid  = threadIdx.x;
    const int lane = tid & 63, wave = tid >> 6;
    const int col  = lane & 15, quad = lane >> 4;
    const int wm   = (wave & 1) * 64, wn = (wave >> 1) * 64;
    const int r0   = blockIdx.y * 128, c0 = blockIdx.x * 128;

    const int f0 = tid * 8;                       // flat elem offset (16B/lane)
    const int row0 = f0 >> 5, kc0 = f0 & 31;
    const size_t aoff0 = (size_t)(r0 + row0) * DIM_ + kc0;
    const size_t aoff1 = (size_t)(r0 + 64 + row0) * DIM_ + kc0;
    const size_t boff0 = (size_t)(c0 + row0) * DIM_ + kc0;
    const size_t boff1 = (size_t)(c0 + 64 + row0) * DIM_ + kc0;
    ushort* asb0 = &As[wave * 512];        // wave-uniform LDS bases
    ushort* asb1 = &As[2048 + wave * 512];
    ushort* bsb0 = &Bs[wave * 512];
    ushort* bsb1 = &Bs[2048 + wave * 512];

    f4v acc[4][4];
    #pragma unroll
    for (int i = 0; i < 4; ++i)
        #pragma unroll
        for (int j = 0; j < 4; ++j) acc[i][j] = (f4v){0.f, 0.f, 0.f, 0.f};

    for (int kk = 0; kk < DIM_; kk += 32) {
        gl_lds16(&A[aoff0 + kk],  asb0);
        gl_lds16(&A[aoff1 + kk],  asb1);
        gl_lds16(&Bw[boff0 + kk], bsb0);
        gl_lds16(&Bw[boff1 + kk], bsb1);
        __syncthreads();
        s8v af[4], bf[4];
        #pragma unroll
        for (int i = 0; i < 4; ++i)
            af[i] = *(const s8v*)&As[(wm + i * 16 + col) * 32 + quad * 8];
        #pragma unroll
        for (int j = 0; j < 4; ++j)
            bf[j] = *(const s8v*)&Bs[(wn + j * 16 + col) * 32 + quad * 8];
        #pragma unroll
        for (int i = 0; i < 4; ++i)
            #pragma unroll
            for (int j = 0; j < 4; ++j)
                acc[i][j] = __builtin_amdgcn_mfma_f32_16x16x32_bf16(af[i], bf[j], acc[i][j], 0, 0, 0);
        __syncthreads();
    }

    float bb[4] = {0.f, 0.f, 0.f, 0.f};
    if (BIAS) {
        #pragma unroll
        for (int j = 0; j < 4; ++j) bb[j] = bias[c0 + wn + j * 16 + col];
    }
    #pragma unroll
    for (int i = 0; i < 4; ++i) {
        #pragma unroll
        for (int r = 0; r < 4; ++r) {
            const size_t grow = (size_t)(r0 + wm + i * 16 + quad * 4 + r);
            #pragma unroll
            for (int j = 0; j < 4; ++j)
                stf(&C[grow * DIM_ + c0 + wn + j * 16 + col], acc[i][j][r] + bb[j]);
        }
    }
    if (DIAG) {
        const int hglob = (c0 + wn) >> 6;
        #pragma unroll
        for (int i = 0; i < 4; ++i) {
            #pragma unroll
            for (int r = 0; r < 4; ++r) {
                float s = 0.f;
                #pragma unroll
                for (int j = 0; j < 4; ++j) s += acc[i][j][r] * acc[i][j][r];
                s += __shfl_xor(s, 1); s += __shfl_xor(s, 2);
                s += __shfl_xor(s, 4); s += __shfl_xor(s, 8);
                if (col == 0)
                    diag[(size_t)(r0 + wm + i * 16 + quad * 4 + r) * H_ + hglob] = DIAGC * s;
            }
        }
    }
}

// ---------------------------------------------------------------------------
// Pass 1: global max over (n,m) of kdash per bh. No stores. Grid (16, 32).
// ---------------------------------------------------------------------------
__launch_bounds__(256)
__global__ void kmax_mfma(const ushort* __restrict__ Kb, const ushort* __restrict__ projb,
                          unsigned* __restrict__ kmaxb)
{
    __shared__ ushort Pl[MP_ * 64];   // 36864 B
    __shared__ float wmx[4];
    const int tid  = threadIdx.x;
    const int lane = tid & 63, wave = tid >> 6;
    const int col  = lane & 15, quad = lane >> 4;
    const int bh   = blockIdx.y, b = bh >> 4, h = bh & 15;

    for (int i = tid * 8; i < MP_ * 64; i += 2048)
        *(uint4*)&Pl[i] = *(const uint4*)&projb[i];
    __syncthreads();

    float mx = -3.4e38f;
    for (int ni = 0; ni < 4; ++ni) {
        const int nb = blockIdx.x * 256 + ni * 64;
        const size_t arow = ((size_t)(b * N_ + nb + wave * 16 + col)) * DIM_ + h * 64 + quad * 8;
        const s8v af0 = *(const s8v*)&Kb[arow];
        const s8v af1 = *(const s8v*)&Kb[arow + 32];
        #pragma unroll
        for (int t = 0; t < 17; ++t) {
            const s8v bf0 = *(const s8v*)&Pl[(t * 16 + col) * 64 + quad * 8];
            const s8v bf1 = *(const s8v*)&Pl[(t * 16 + col) * 64 + 32 + quad * 8];
            f4v a = (f4v){0.f, 0.f, 0.f, 0.f};
            a = __builtin_amdgcn_mfma_f32_16x16x32_bf16(af0, bf0, a, 0, 0, 0);
            a = __builtin_amdgcn_mfma_f32_16x16x32_bf16(af1, bf1, a, 0, 0, 0);
            if (t * 16 + col < M_) {
                #pragma unroll
                for (int r = 0; r < 4; ++r) mx = fmaxf(mx, a[r]);
            }
        }
    }
    #pragma unroll
    for (int o = 32; o > 0; o >>= 1) mx = fmaxf(mx, __shfl_xor(mx, o));
    if (lane == 0) wmx[wave] = mx;
    __syncthreads();
    if (tid == 0)
        atomicMax(&kmaxb[bh], encf(fmaxf(fmaxf(wmx[0], wmx[1]), fmaxf(wmx[2], wmx[3]))));
}

// ---------------------------------------------------------------------------
// Pass 2: partial ctx/kcs per n-chunk, NO atomics. Grid (NCH, 32).
// ctxp[bh][chunk][m][e] (fp32), kcsp[bh][chunk][m].
// ---------------------------------------------------------------------------
__launch_bounds__(256)
__global__ void kctx_mfma(const ushort* __restrict__ Kb, const ushort* __restrict__ Vb,
                          const ushort* __restrict__ projb,
                          const float* __restrict__ diagK, const unsigned* __restrict__ kmaxb,
                          float* __restrict__ ctxp, float* __restrict__ kcsp)
{
    __shared__ ushort Pl[MP_ * 64];    // 36864 B (proj, resident)
    __shared__ ushort Kp[MP_ * LKN];   // 23040 B (kp^T tile [m][n32])
    __shared__ ushort Vt[64 * LKN];    //  5120 B (V^T tile [e][n32])
    __shared__ float kred[2][MP_];     //  2304 B

    const int tid  = threadIdx.x;
    const int lane = tid & 63, wave = tid >> 6;
    const int col  = lane & 15, quad = lane >> 4;
    const int bh   = blockIdx.y, b = bh >> 4, h = bh & 15;
    const int n0   = blockIdx.x * (N_ / NCH);
    const float kmax = decf(kmaxb[bh]);
    const int rowblk = wave >> 1;            // waves 0,1 -> n-rows 0-15; 2,3 -> 16-31
    const int t0 = (wave & 1) * 9;           // m-tiles: 0..8 / 9..17 (covers all 18)
    const int t1 = t0 + 9;

    for (int i = tid * 8; i < MP_ * 64; i += 2048)
        *(uint4*)&Pl[i] = *(const uint4*)&projb[i];

    f4v facc[18];
    #pragma unroll
    for (int t = 0; t < 18; ++t) facc[t] = (f4v){0.f, 0.f, 0.f, 0.f};
    float kcsa[9] = {};

    __syncthreads();

    for (int ks = 0; ks < (N_ / NCH) / 32; ++ks) {
        const int nb = n0 + ks * 32;
        // V^T stage: thread handles n = tid&31, e = (tid>>5)*8 .. +7
        {
            const int n = tid & 31, e0 = (tid >> 5) * 8;
            const s8v vv = *(const s8v*)&Vb[((size_t)(b * N_ + nb + n)) * DIM_ + h * 64 + e0];
            #pragma unroll
            for (int j = 0; j < 8; ++j) Vt[(e0 + j) * LKN + n] = ((const ushort*)&vv)[j];
        }
        // dd via MFMA: A-rows = K rows nb + rowblk*16 + col
        const size_t arow = ((size_t)(b * N_ + nb + rowblk * 16 + col)) * DIM_ + h * 64 + quad * 8;
        const s8v af0 = *(const s8v*)&Kb[arow];
        const s8v af1 = *(const s8v*)&Kb[arow + 32];
        float dgr[4];
        #pragma unroll
        for (int r = 0; r < 4; ++r)
            dgr[r] = diagK[((size_t)(b * N_ + nb + rowblk * 16 + quad * 4 + r)) * H_ + h];
        for (int t = t0; t < t1; ++t) {
            const s8v bf0 = *(const s8v*)&Pl[(t * 16 + col) * 64 + quad * 8];
            const s8v bf1 = *(const s8v*)&Pl[(t * 16 + col) * 64 + 32 + quad * 8];
            f4v a = (f4v){0.f, 0.f, 0.f, 0.f};
            a = __builtin_amdgcn_mfma_f32_16x16x32_bf16(af0, bf0, a, 0, 0, 0);
            a = __builtin_amdgcn_mfma_f32_16x16x32_bf16(af1, bf1, a, 0, 0, 0);
            const int m = t * 16 + col;
            float kp[4];
            #pragma unroll
            for (int r = 0; r < 4; ++r) {
                float v = 0.f;
                if (m < M_) v = RATIOC * (__expf(a[r] - dgr[r] - kmax) + EPSC);
                kp[r] = v;
            }
            kcsa[t - t0] += kp[0] + kp[1] + kp[2] + kp[3];
            ushort4 pk;
            pk.x = f2bu(kp[0]); pk.y = f2bu(kp[1]); pk.z = f2bu(kp[2]); pk.w = f2bu(kp[3]);
            *(ushort4*)&Kp[m * LKN + rowblk * 16 + quad * 4] = pk;   // 4 consecutive n
        }
        __syncthreads();
        // out: wave owns e-tile = wave*16, all 18 m-tiles, k = 32 (this chunk)
        const s8v bfe = *(const s8v*)&Vt[(wave * 16 + col) * LKN + quad * 8];
        #pragma unroll
        for (int t = 0; t < 18; ++t) {
            const s8v am = *(const s8v*)&Kp[(t * 16 + col) * LKN + quad * 8];
            facc[t] = __builtin_amdgcn_mfma_f32_16x16x32_bf16(am, bfe, facc[t], 0, 0, 0);
        }
        __syncthreads();
    }

    // partial ctx: plain stores (D layout: m = t*16+quad*4+r, e = wave*16+col)
    const size_t pbase = ((size_t)bh * NCH + blockIdx.x) * (MP_ * 64);
    #pragma unroll
    for (int t = 0; t < 18; ++t) {
        #pragma unroll
        for (int r = 0; r < 4; ++r)
            ctxp[pbase + (size_t)(t * 16 + quad * 4 + r) * 64 + wave * 16 + col] = facc[t][r];
    }
    // partial kcs via LDS combine (waves 0/1 -> kred[0], 2/3 -> kred[1])
    for (int t = t0; t < t1; ++t) {
        float s = kcsa[t - t0];
        s += __shfl_xor(s, 16);
        s += __shfl_xor(s, 32);
        if (quad == 0) kred[rowblk][t * 16 + col] = s;
    }
    __syncthreads();
    for (int i = tid; i < MP_; i += 256)
        kcsp[((size_t)bh * NCH + blockIdx.x) * MP_ + i] = kred[0][i] + kred[1][i];
}

// ---------------------------------------------------------------------------
// Reduce partials: ctxT[bh][e][m] (bf16) + kcs[bh][m]. Grid (8, 32).
// ---------------------------------------------------------------------------
__launch_bounds__(256)
__global__ void ctx_reduce(const float* __restrict__ ctxp, const float* __restrict__ kcsp,
                           ushort* __restrict__ ctxT, float* __restrict__ kcs)
{
    const int bh = blockIdx.y, tid = threadIdx.x;
    const int base = blockIdx.x * (MP_ * 64 / 8);   // 2304
    const size_t cb = (size_t)bh * NCH * (MP_ * 64);
    #pragma unroll
    for (int u = 0; u < 9; ++u) {
        const int flat = base + u * 256 + tid;
        float s = 0.f;
        #pragma unroll
        for (int c = 0; c < NCH; ++c) s += ctxp[cb + (size_t)c * (MP_ * 64) + flat];
        const int m = flat >> 6, e = flat & 63;
        ctxT[((size_t)bh * 64 + e) * MP_ + m] = f2bu(s);
    }
    if (blockIdx.x == 0) {
        for (int i = tid; i < MP_; i += 256) {
            float s = 0.f;
            #pragma unroll
            for (int c = 0; c < NCH; ++c) s += kcsp[((size_t)bh * NCH + c) * MP_ + i];
            kcs[(size_t)bh * MP_ + i] = s;
        }
    }
}

// ---------------------------------------------------------------------------
// Fused Q path: dash MFMA (proj in LDS) -> rowmax/exp/den in regs -> qp to
// LDS (C-layout -> A-layout transpose) -> restage LDS with ctxT -> PV MFMA
// -> scaled store to Ab. Grid (64, 32).
// ---------------------------------------------------------------------------
__launch_bounds__(256)
__global__ void qdashout(const ushort* __restrict__ Qb, const ushort* __restrict__ projb,
                         const float* __restrict__ diagQ, const float* __restrict__ kcs,
                         const ushort* __restrict__ ctxT, ushort* __restrict__ Ab)
{
    __shared__ ushort UB[64 * LSB];   // 37888 B: proj (flat) then ctxT ([e][LSB])
    __shared__ ushort qpl[64 * LSB];  // 37888 B: qp tile [n][m], stride LSB
    __shared__ float kcl[MP_];
    __shared__ float dinv[64];

    const int tid  = threadIdx.x;
    const int lane = tid & 63, wave = tid >> 6;
    const int col  = lane & 15, quad = lane >> 4;
    const int bh   = blockIdx.y, b = bh >> 4, h = bh & 15;
    const int n0   = blockIdx.x * 64;

    for (int i = tid * 8; i < MP_ * 64; i += 2048)
        *(uint4*)&UB[i] = *(const uint4*)&projb[i];
    for (int i = tid; i < MP_; i += 256) kcl[i] = kcs[(size_t)bh * MP_ + i];
    __syncthreads();

    // dash: C rows n = wave*16 + quad*4 + r, cols m = t*16 + col
    const size_t arow = ((size_t)(b * N_ + n0 + wave * 16 + col)) * DIM_ + h * 64 + quad * 8;
    const s8v af0 = *(const s8v*)&Qb[arow];
    const s8v af1 = *(const s8v*)&Qb[arow + 32];

    f4v acc[17];
    #pragma unroll
    for (int t = 0; t < 17; ++t) {
        const s8v bf0 = *(const s8v*)&UB[(t * 16 + col) * 64 + quad * 8];
        const s8v bf1 = *(const s8v*)&UB[(t * 16 + col) * 64 + 32 + quad * 8];
        f4v a = (f4v){0.f, 0.f, 0.f, 0.f};
        a = __builtin_amdgcn_mfma_f32_16x16x32_bf16(af0, bf0, a, 0, 0, 0);
        a = __builtin_amdgcn_mfma_f32_16x16x32_bf16(af1, bf1, a, 0, 0, 0);
        acc[t] = a;
    }

    float dgr[4], rmx[4];
    #pragma unroll
    for (int r = 0; r < 4; ++r) {
        const int gn = n0 + wave * 16 + quad * 4 + r;
        dgr[r] = diagQ[((size_t)(b * N_ + gn)) * H_ + h];
        float mx = -3.4e38f;
        #pragma unroll
        for (int t = 0; t < 16; ++t) mx = fmaxf(mx, acc[t][r]);
        if (col < 10) mx = fmaxf(mx, acc[16][r]);
        mx = fmaxf(mx, __shfl_xor(mx, 1));
        mx = fmaxf(mx, __shfl_xor(mx, 2));
        mx = fmaxf(mx, __shfl_xor(mx, 4));
        mx = fmaxf(mx, __shfl_xor(mx, 8));
        rmx[r] = mx;
    }

    float den[4] = {0.f, 0.f, 0.f, 0.f};
    #pragma unroll
    for (int t = 0; t < 17; ++t) {
        const int m = t * 16 + col;
        const float kc = kcl[m];
        #pragma unroll
        for (int r = 0; r < 4; ++r) {
            float v = 0.f;
            if (m < M_)
                v = RATIOC * (__expf(acc[t][r] - dgr[r] - rmx[r]) + EPSC);
            acc[t][r] = v;
            den[r] += v * kc;
        }
    }

    // qp -> LDS in A-layout-ready form: qpl[n][m], zero m in [272, 288)
    #pragma unroll
    for (int r = 0; r < 4; ++r) {
        const int rb = (wave * 16 + quad * 4 + r) * LSB;
        #pragma unroll
        for (int t = 0; t < 17; ++t)
            qpl[rb + t * 16 + col] = f2bu(acc[t][r]);
        if (col < 8) *(uint*)&qpl[rb + 272 + col * 2] = 0u;
    }
    #pragma unroll
    for (int r = 0; r < 4; ++r) {
        float d = den[r];
        d += __shfl_xor(d, 1); d += __shfl_xor(d, 2);
        d += __shfl_xor(d, 4); d += __shfl_xor(d, 8);
        if (col == 0)
            dinv[wave * 16 + quad * 4 + r] = 1.0f / fmaxf(d, 1e-30f);
    }
    __syncthreads();

    // restage UB with ctxT rows [e][m] at stride LSB
    for (int i = tid * 8; i < 64 * MP_; i += 2048) {
        const int e = i / MP_, m = i - e * MP_;
        *(uint4*)&UB[e * LSB + m] = *(const uint4*)&ctxT[(size_t)bh * 64 * MP_ + i];
    }
    __syncthreads();

    // PV: A rows n = wave*16+col (from qpl), B rows e = j*16+col (from UB)
    f4v acc2[4];
    #pragma unroll
    for (int j = 0; j < 4; ++j) acc2[j] = (f4v){0.f, 0.f, 0.f, 0.f};
    #pragma unroll
    for (int kk = 0; kk < 9; ++kk) {
        const s8v afr = *(const s8v*)&qpl[(wave * 16 + col) * LSB + kk * 32 + quad * 8];
        #pragma unroll
        for (int j = 0; j < 4; ++j) {
            const s8v bfr = *(const s8v*)&UB[(j * 16 + col) * LSB + kk * 32 + quad * 8];
            acc2[j] = __builtin_amdgcn_mfma_f32_16x16x32_bf16(afr, bfr, acc2[j], 0, 0, 0);
        }
    }
    #pragma unroll
    for (int j = 0; j < 4; ++j) {
        #pragma unroll
        for (int r = 0; r < 4; ++r) {
            const int n = wave * 16 + quad * 4 + r;
            Ab[((size_t)(b * N_ + n0 + n)) * DIM_ + h * 64 + j * 16 + col] =
                f2bu(acc2[j][r] * dinv[n]);
        }
    }
}

// ---------------------------------------------------------------------------
extern "C" void kernel_launch(void* const* d_in, const int* in_sizes, int n_in,
                              void* d_out, int out_size, void* d_ws, size_t ws_size,
                              hipStream_t stream)
{
    const float* x    = (const float*)d_in[0];
    const float* Wq   = (const float*)d_in[1];
    const float* Wk   = (const float*)d_in[2];
    const float* Wv   = (const float*)d_in[3];
    const float* Wo   = (const float*)d_in[4];
    const float* bo   = (const float*)d_in[5];
    const float* proj = (const float*)d_in[6];

    char* ws = (char*)d_ws;
    size_t o = 0;
    ushort* xb    = (ushort*)(ws + o); o += (size_t)RT_ * DIM_ * 2;
    ushort* Wqb   = (ushort*)(ws + o); o += (size_t)DIM_ * DIM_ * 2;
    ushort* Wkb   = (ushort*)(ws + o); o += (size_t)DIM_ * DIM_ * 2;
    ushort* Wvb   = (ushort*)(ws + o); o += (size_t)DIM_ * DIM_ * 2;
    ushort* Wob   = (ushort*)(ws + o); o += (size_t)DIM_ * DIM_ * 2;
    ushort* projb = (ushort*)(ws + o); o += (size_t)MP_ * 64 * 2;
    ushort* Qb    = (ushort*)(ws + o); o += (size_t)RT_ * DIM_ * 2;
    ushort* Kb    = (ushort*)(ws + o); o += (size_t)RT_ * DIM_ * 2;
    ushort* Vb    = (ushort*)(ws + o); o += (size_t)RT_ * DIM_ * 2;
    ushort* Ab    = (ushort*)(ws + o); o += (size_t)RT_ * DIM_ * 2;
    float*    ctxp  = (float*)(ws + o);    o += (size_t)BH_ * NCH * MP_ * 64 * 4;  // 37.75 MB
    float*    kcsp  = (float*)(ws + o);    o += (size_t)BH_ * NCH * MP_ * 4;
    float*    kcs   = (float*)(ws + o);    o += (size_t)BH_ * MP_ * 4;
    unsigned* kmaxb = (unsigned*)(ws + o); o += 128;
    float*    diagQ = (float*)(ws + o);    o += (size_t)RT_ * H_ * 4;
    float*    diagK = (float*)(ws + o);    o += (size_t)RT_ * H_ * 4;
    ushort*   ctxT  = (ushort*)(ws + o);   o += (size_t)BH_ * 64 * MP_ * 2;

    hipMemsetAsync(kmaxb, 0, 128, stream);   // encf(0) < any real max

    cast_x<<<dim3(RT_ * DIM_ / 2048), 256, 0, stream>>>(x, xb);
    cast_w<<<dim3(DIM_ * DIM_ / 2048, 4), 256, 0, stream>>>(Wq, Wk, Wv, Wo, Wqb, Wkb, Wvb, Wob);
    cast_proj<<<dim3(MP_ * 64 / 256), 256, 0, stream>>>(proj, projb);

    const dim3 ggrid(DIM_ / 128, RT_ / 128);   // (8, 64)
    gemm128<true,  false, __hip_bfloat16><<<ggrid, 256, 0, stream>>>(xb, Wqb, nullptr, (__hip_bfloat16*)Qb, diagQ);
    gemm128<true,  false, __hip_bfloat16><<<ggrid, 256, 0, stream>>>(xb, Wkb, nullptr, (__hip_bfloat16*)Kb, diagK);
    gemm128<false, false, __hip_bfloat16><<<ggrid, 256, 0, stream>>>(xb, Wvb, nullptr, (__hip_bfloat16*)Vb, nullptr);

    kmax_mfma<<<dim3(16, BH_), 256, 0, stream>>>(Kb, projb, kmaxb);
    kctx_mfma<<<dim3(NCH, BH_), 256, 0, stream>>>(Kb, Vb, projb, diagK, kmaxb, ctxp, kcsp);
    ctx_reduce<<<dim3(8, BH_), 256, 0, stream>>>(ctxp, kcsp, ctxT, kcs);
    qdashout<<<dim3(N_ / 64, BH_), 256, 0, stream>>>(Qb, projb, diagQ, kcs, ctxT, Ab);

    gemm128<false, true, float><<<ggrid, 256, 0, stream>>>(Ab, Wob, bo, (float*)d_out, nullptr);
}